// Round 2
// baseline (5663.141 us; speedup 1.0000x reference)
//
#include <hip/hip_runtime.h>
#include <hip/hip_bf16.h>
#include <math.h>

#define Bq 2
#define Sq 1024
#define Dq 1024
#define Hq 16
#define DHq 64
#define FFq 4096
#define Eq 4
#define Kq 64
#define Mq 256
#define GATEq 128
#define BSq (Bq*Sq)
#define DEPTHF 1.25f
#define SCALEF 0.125f

typedef __hip_bfloat16 bf16;

__device__ __forceinline__ float toF(float v){ return v; }
__device__ __forceinline__ float toF(bf16 v){ return __bfloat162float(v); }
__device__ __forceinline__ void stF(float* p, size_t i, float v){ p[i] = v; }
__device__ __forceinline__ void stF(bf16* p, size_t i, float v){ p[i] = __float2bfloat16(v); }
__device__ __forceinline__ float gelu_f(float x){
  const float c = 0.7978845608028654f;
  return 0.5f*x*(1.0f + tanhf(c*(x + 0.044715f*x*x*x)));
}

// ---------------- dtype detector: bf16 data -> low16 of each u32 word has clustered exponent ----------------
__global__ __launch_bounds__(256)
void detect_kernel(const unsigned* __restrict__ xw, int* __restrict__ flag)
{
  __shared__ int cnt;
  if (threadIdx.x == 0) cnt = 0;
  __syncthreads();
  int c = 0;
  for (int i = threadIdx.x; i < 4096; i += 256) {
    unsigned e = (xw[i] >> 7) & 0xFFu;           // exponent field of low-half bf16
    c += (e >= 0x70u && e <= 0x8Fu) ? 1 : 0;
  }
#pragma unroll
  for (int o = 32; o >= 1; o >>= 1) c += __shfl_xor(c, o);
  if ((threadIdx.x & 63) == 0) atomicAdd(&cnt, c);
  __syncthreads();
  if (threadIdx.x == 0) *flag = (cnt > 2048) ? 1 : 0;   // ~4000 if bf16, ~512 if fp32
}

// ---------------- generic tiled GEMM body: C = [acc +] rowscale * (act(A@W + bias)) ----------------
template<typename AT, typename WT, typename CT>
__device__ void gemm_body(float (*As)[17], float (*Bs)[65],
                          const AT* __restrict__ A, const WT* __restrict__ Bw,
                          const WT* __restrict__ bias, unsigned wOff, unsigned bOff,
                          const float* __restrict__ rowscale,
                          CT* __restrict__ C, int M, int N, int K,
                          int accumulate, int act)
{
  Bw += wOff;
  if (bias) bias += bOff;
  int tid = threadIdx.x;
  int tx = tid & 15, ty = tid >> 4;
  int bm = blockIdx.x * 64, bn = blockIdx.y * 64;
  float c[4][4] = {};
  for (int k0 = 0; k0 < K; k0 += 16) {
#pragma unroll
    for (int i = 0; i < 4; i++) {
      int l = tid + 256*i;
      int m = l >> 4, kk = l & 15;
      As[m][kk] = toF(A[(size_t)(bm+m)*K + (k0+kk)]);
    }
#pragma unroll
    for (int i = 0; i < 4; i++) {
      int l = tid + 256*i;
      int kk = l >> 6, n = l & 63;
      Bs[kk][n] = toF(Bw[(size_t)(k0+kk)*N + (bn+n)]);
    }
    __syncthreads();
#pragma unroll
    for (int kk = 0; kk < 16; kk++) {
      float a[4], bb[4];
#pragma unroll
      for (int i=0;i<4;i++) a[i] = As[ty*4+i][kk];
#pragma unroll
      for (int j=0;j<4;j++) bb[j] = Bs[kk][tx*4+j];
#pragma unroll
      for (int i=0;i<4;i++)
#pragma unroll
        for (int j=0;j<4;j++) c[i][j] += a[i]*bb[j];
    }
    __syncthreads();
  }
#pragma unroll
  for (int i=0;i<4;i++) {
    int row = bm + ty*4+i;
    float rs = rowscale ? rowscale[row] : 1.0f;
#pragma unroll
    for (int j=0;j<4;j++) {
      int col = bn + tx*4+j;
      float v = c[i][j];
      if (bias) v += toF(bias[col]);
      if (act) v = gelu_f(v);
      v *= rs;
      size_t idx = (size_t)row*N + col;
      if (accumulate) v += toF(C[idx]);
      stF(C, idx, v);
    }
  }
}

// A = x (input dtype), W = input dtype, C = bf16
__global__ __launch_bounds__(256)
void gemm_xw(const int* __restrict__ flag, const void* A, const void* W, const void* bias,
             unsigned wOff, unsigned bOff, const float* rowscale, bf16* C,
             int M, int N, int K, int accumulate, int act)
{
  __shared__ float As[64][17];
  __shared__ float Bs[16][65];
  if (*flag) gemm_body<bf16,bf16,bf16>(As, Bs, (const bf16*)A, (const bf16*)W, (const bf16*)bias, wOff, bOff, rowscale, C, M, N, K, accumulate, act);
  else       gemm_body<float,float,bf16>(As, Bs, (const float*)A, (const float*)W, (const float*)bias, wOff, bOff, rowscale, C, M, N, K, accumulate, act);
}

// A = bf16 intermediate, W = input dtype, C = fp32 accumulator
__global__ __launch_bounds__(256)
void gemm_bwf(const int* __restrict__ flag, const bf16* A, const void* W, const void* bias,
              unsigned wOff, unsigned bOff, const float* rowscale, float* C,
              int M, int N, int K, int accumulate, int act)
{
  __shared__ float As[64][17];
  __shared__ float Bs[16][65];
  if (*flag) gemm_body<bf16,bf16,float>(As, Bs, A, (const bf16*)W, (const bf16*)bias, wOff, bOff, rowscale, C, M, N, K, accumulate, act);
  else       gemm_body<bf16,float,float>(As, Bs, A, (const float*)W, (const float*)bias, wOff, bOff, rowscale, C, M, N, K, accumulate, act);
}

// A = bf16 intermediate, W = input dtype, C = bf16
__global__ __launch_bounds__(256)
void gemm_bwb(const int* __restrict__ flag, const bf16* A, const void* W, const void* bias,
              unsigned wOff, unsigned bOff, const float* rowscale, bf16* C,
              int M, int N, int K, int accumulate, int act)
{
  __shared__ float As[64][17];
  __shared__ float Bs[16][65];
  if (*flag) gemm_body<bf16,bf16,bf16>(As, Bs, A, (const bf16*)W, (const bf16*)bias, wOff, bOff, rowscale, C, M, N, K, accumulate, act);
  else       gemm_body<bf16,float,bf16>(As, Bs, A, (const float*)W, (const float*)bias, wOff, bOff, rowscale, C, M, N, K, accumulate, act);
}

// ---------------- fused softmax attention (dense / top-K sparse), 8 query rows / block ----------------
template<int SPARSE>
__global__ __launch_bounds__(256)
void attn_kernel(const bf16* __restrict__ Q, const bf16* __restrict__ Kb,
                 const bf16* __restrict__ V, bf16* __restrict__ O)
{
  const int ROWS = 8;
  int blk = blockIdx.x;
  int rb = blk & (Sq/ROWS - 1);
  int h  = (blk / (Sq/ROWS)) & (Hq-1);
  int b  = blk / ((Sq/ROWS)*Hq);
  __shared__ float qs[ROWS][DHq];
  __shared__ float sc[ROWS][Sq];      // 32 KB
  __shared__ float rowl[ROWS];
  int tid = threadIdx.x;
  size_t base = ((size_t)b*Sq)*Dq + (size_t)h*DHq;
  int q0 = rb*ROWS;
  for (int l = tid; l < ROWS*DHq; l += 256) {
    int r = l >> 6, d = l & 63;
    qs[r][d] = toF(Q[base + (size_t)(q0+r)*Dq + d]);
  }
  __syncthreads();
  for (int j = tid; j < Sq; j += 256) {
    const bf16* kp = &Kb[base + (size_t)j*Dq];
    float acc[ROWS] = {0,0,0,0,0,0,0,0};
    for (int d = 0; d < DHq; d++) {
      float kd = toF(kp[d]);
#pragma unroll
      for (int r = 0; r < ROWS; r++) acc[r] += qs[r][d]*kd;
    }
#pragma unroll
    for (int r = 0; r < ROWS; r++) sc[r][j] = acc[r]*SCALEF;
  }
  __syncthreads();
  {
    int r = tid >> 5, sub = tid & 31;
    float thrf = -1e30f;
    if (SPARSE) {
      unsigned uu[32];
#pragma unroll
      for (int i=0;i<32;i++) {
        unsigned ub = __float_as_uint(sc[r][sub + 32*i]);
        uu[i] = (ub & 0x80000000u) ? ~ub : (ub | 0x80000000u);
      }
      unsigned lo = 0u;
#pragma unroll
      for (int bit = 31; bit >= 0; bit--) {
        unsigned cand = lo | (1u << bit);
        int c = 0;
#pragma unroll
        for (int i=0;i<32;i++) c += (uu[i] >= cand) ? 1 : 0;
#pragma unroll
        for (int o=16;o>=1;o>>=1) c += __shfl_xor(c, o, 32);
        if (c >= Kq) lo = cand;
      }
      thrf = (lo & 0x80000000u) ? __uint_as_float(lo & 0x7FFFFFFFu)
                                : __uint_as_float(~lo);
    }
    float m = -1e30f;
    for (int j = sub; j < Sq; j += 32) {
      float f = sc[r][j];
      if (!SPARSE || f >= thrf) m = fmaxf(m, f);
    }
#pragma unroll
    for (int o=16;o>=1;o>>=1) m = fmaxf(m, __shfl_xor(m, o, 32));
    float lsum = 0.f;
    for (int j = sub; j < Sq; j += 32) {
      float f = sc[r][j];
      float p = (!SPARSE || f >= thrf) ? __expf(f - m) : 0.f;
      sc[r][j] = p;
      lsum += p;
    }
#pragma unroll
    for (int o=16;o>=1;o>>=1) lsum += __shfl_xor(lsum, o, 32);
    if (sub == 0) rowl[r] = fmaxf(lsum, 1e-30f);
  }
  __syncthreads();
  int d = tid & 63;
  int rr = tid >> 6;
  float a0 = 0.f, a1 = 0.f;
  for (int j = 0; j < Sq; j++) {
    float v = toF(V[base + (size_t)j*Dq + d]);
    a0 += sc[rr][j]*v;
    a1 += sc[rr+4][j]*v;
  }
  stF(O, base + (size_t)(q0+rr)*Dq + d,   a0 / rowl[rr]);
  stF(O, base + (size_t)(q0+rr+4)*Dq + d, a1 / rowl[rr+4]);
}

// ---------------- performer pass 1: kv = pk^T v, z = sum pk (atomic accumulate) ----------------
template<typename WT>
__device__ void perf_kv_body(bf16* wfs, float* krow, float* vrow, float* pkrow,
                             const bf16* __restrict__ Kb, const bf16* __restrict__ V,
                             const WT* __restrict__ wf, float* __restrict__ kv,
                             float* __restrict__ z)
{
  const int SLEN = Sq/8;
  int bh = blockIdx.x;
  int chunk = blockIdx.y;
  int h = bh & (Hq-1), b = bh >> 4;
  int tid = threadIdx.x;
  for (int l = tid; l < DHq*Mq; l += 256)
    wfs[l] = __float2bfloat16(toF(wf[l]));
  int d = tid & 63, g = tid >> 6;
  float kvacc[64];
#pragma unroll
  for (int i=0;i<64;i++) kvacc[i]=0.f;
  float zacc = 0.f;
  size_t base = ((size_t)b*Sq)*Dq + (size_t)h*DHq;
  for (int s = chunk*SLEN; s < (chunk+1)*SLEN; s++) {
    __syncthreads();
    if (tid < 64)       krow[tid]    = toF(Kb[base + (size_t)s*Dq + tid]);
    else if (tid < 128) vrow[tid-64] = toF(V [base + (size_t)s*Dq + (tid-64)]);
    __syncthreads();
    float a = 0.f;
#pragma unroll
    for (int dd = 0; dd < DHq; dd++) a += krow[dd]*toF(wfs[dd*Mq + tid]);
    float pk = fmaxf(a, 0.f);
    pkrow[tid] = pk;
    zacc += pk;
    __syncthreads();
    float vd = vrow[d];
#pragma unroll
    for (int i = 0; i < 64; i++) kvacc[i] += pkrow[g*64+i]*vd;
  }
  float* kvp = kv + (size_t)bh*Mq*DHq;
  for (int i = 0; i < 64; i++) atomicAdd(&kvp[(size_t)(g*64+i)*DHq + d], kvacc[i]);
  atomicAdd(&z[(size_t)bh*Mq + tid], zacc);
}

__global__ __launch_bounds__(256)
void perf_kv_kernel(const int* __restrict__ flag, const bf16* Kb, const bf16* V,
                    const void* wf, float* kv, float* z)
{
  __shared__ bf16 wfs[DHq*Mq];
  __shared__ float krow[DHq], vrow[DHq], pkrow[Mq];
  if (*flag) perf_kv_body<bf16>(wfs, krow, vrow, pkrow, Kb, V, (const bf16*)wf, kv, z);
  else       perf_kv_body<float>(wfs, krow, vrow, pkrow, Kb, V, (const float*)wf, kv, z);
}

// ---------------- performer pass 2: out = (pq @ kv) / (pq.z + 1e-6) ----------------
template<typename WT>
__device__ void perf_out_body(bf16* wfs, float* qrow, float* pqrow, float* redn, float* redd,
                              const bf16* __restrict__ Q, const WT* __restrict__ wf,
                              const float* __restrict__ kv, const float* __restrict__ z,
                              bf16* __restrict__ O)
{
  const int TC = 64;
  int blk = blockIdx.x;
  int tc = blk & (Sq/TC - 1);
  int h = (blk / (Sq/TC)) & (Hq-1);
  int b = blk / ((Sq/TC)*Hq);
  int bh = b*Hq + h;
  int tid = threadIdx.x;
  for (int l = tid; l < DHq*Mq; l += 256)
    wfs[l] = __float2bfloat16(toF(wf[l]));
  int d = tid & 63, g = tid >> 6;
  size_t base = ((size_t)b*Sq)*Dq + (size_t)h*DHq;
  const float* kvp = kv + (size_t)bh*Mq*DHq;
  const float* zp  = z  + (size_t)bh*Mq;
  for (int s = tc*TC; s < (tc+1)*TC; s++) {
    __syncthreads();
    if (tid < 64) qrow[tid] = toF(Q[base + (size_t)s*Dq + tid]);
    __syncthreads();
    float a = 0.f;
#pragma unroll
    for (int dd = 0; dd < DHq; dd++) a += qrow[dd]*toF(wfs[dd*Mq + tid]);
    float pq = fmaxf(a, 0.f);
    pqrow[tid] = pq;
    float pd = pq * zp[tid];
#pragma unroll
    for (int o=32;o>=1;o>>=1) pd += __shfl_xor(pd, o);
    if ((tid & 63) == 0) redd[g] = pd;
    __syncthreads();
    float den = redd[0]+redd[1]+redd[2]+redd[3] + 1e-6f;
    float np = 0.f;
#pragma unroll
    for (int i = 0; i < 64; i++) np += pqrow[g*64+i]*kvp[(size_t)(g*64+i)*DHq + d];
    redn[g*DHq + d] = np;
    __syncthreads();
    if (g == 0) {
      float num = redn[0*DHq+d]+redn[1*DHq+d]+redn[2*DHq+d]+redn[3*DHq+d];
      stF(O, base + (size_t)s*Dq + d, num / den);
    }
  }
}

__global__ __launch_bounds__(256)
void perf_out_kernel(const int* __restrict__ flag, const bf16* Q, const void* wf,
                     const float* kv, const float* z, bf16* O)
{
  __shared__ bf16 wfs[DHq*Mq];
  __shared__ float qrow[DHq], pqrow[Mq];
  __shared__ float redn[4*DHq];
  __shared__ float redd[4];
  if (*flag) perf_out_body<bf16>(wfs, qrow, pqrow, redn, redd, Q, (const bf16*)wf, kv, z, O);
  else       perf_out_body<float>(wfs, qrow, pqrow, redn, redd, Q, (const float*)wf, kv, z, O);
}

// ---------------- LayerNorm ----------------
// mode 0: v = x(IT) + A(f32)      -> bf16 out
// mode 1: v = A(bf16) + B(bf16)   -> bf16 out
// mode 2: v = A(bf16)             -> IT out (d_out)
template<typename IT>
__device__ void ln_body(float* buf, float* red, const IT* __restrict__ xb,
                        const void* Ap, const void* Bp,
                        const IT* __restrict__ g, const IT* __restrict__ be,
                        void* out, int mode)
{
  int row = blockIdx.x;
  int tid = threadIdx.x;
  size_t off = (size_t)row*Dq;
  for (int dd = tid; dd < Dq; dd += 256) {
    float v;
    if (mode == 0)      v = toF(xb[off+dd]) + ((const float*)Ap)[off+dd];
    else if (mode == 1) v = toF(((const bf16*)Ap)[off+dd]) + toF(((const bf16*)Bp)[off+dd]);
    else                v = toF(((const bf16*)Ap)[off+dd]);
    buf[dd] = v;
  }
  __syncthreads();
  float s = 0.f, q = 0.f;
  for (int dd = tid; dd < Dq; dd += 256) { float v = buf[dd]; s += v; q += v*v; }
#pragma unroll
  for (int o=32;o>=1;o>>=1) { s += __shfl_xor(s,o); q += __shfl_xor(q,o); }
  int w = tid >> 6;
  if ((tid & 63) == 0) { red[w] = s; red[4+w] = q; }
  __syncthreads();
  if (tid == 0) {
    float S1 = red[0]+red[1]+red[2]+red[3];
    float Q1 = red[4]+red[5]+red[6]+red[7];
    float mu = S1 / (float)Dq;
    float var = Q1 / (float)Dq - mu*mu;
    red[8] = mu; red[9] = rsqrtf(fmaxf(var, 0.f) + 1e-5f);
  }
  __syncthreads();
  float mu = red[8], inv = red[9];
  for (int dd = tid; dd < Dq; dd += 256) {
    float v = (buf[dd]-mu)*inv*toF(g[dd]) + toF(be[dd]);
    if (mode == 2) stF((IT*)out, off+dd, v);
    else           stF((bf16*)out, off+dd, v);
  }
}

__global__ __launch_bounds__(256)
void ln_kernel(const int* __restrict__ flag, const void* xb, const void* A, const void* Bv,
               const void* g, const void* be, void* out, int mode)
{
  __shared__ float buf[Dq];
  __shared__ float red[10];
  if (*flag) ln_body<bf16>(buf, red, (const bf16*)xb, A, Bv, (const bf16*)g, (const bf16*)be, out, mode);
  else       ln_body<float>(buf, red, (const float*)xb, A, Bv, (const float*)g, (const float*)be, out, mode);
}

// ---------------- avg over S ----------------
template<typename IT>
__device__ void avg_body(const IT* __restrict__ x, float* __restrict__ avg)
{
  int i = blockIdx.x*256 + threadIdx.x;
  if (i >= Bq*Dq) return;
  int b = i >> 10, dd = i & 1023;
  float s = 0.f;
  for (int ss = 0; ss < Sq; ss++) s += toF(x[((size_t)b*Sq+ss)*Dq + dd]);
  avg[i] = s * (1.0f/(float)Sq);
}

__global__ __launch_bounds__(256)
void avg_kernel(const int* __restrict__ flag, const void* x, float* avg)
{
  if (*flag) avg_body<bf16>((const bf16*)x, avg);
  else       avg_body<float>((const float*)x, avg);
}

// ---------------- MoE router (softmax over E, pre-scaled by ag0*DEPTH) ----------------
template<typename IT>
__device__ void router_body(const IT* __restrict__ x, const IT* __restrict__ wr,
                            const IT* __restrict__ br, const float* __restrict__ cmb0,
                            float* __restrict__ gates_t)
{
  int row = blockIdx.x;
  int tid = threadIdx.x;
  size_t off = (size_t)row*Dq;
  float a0=0,a1=0,a2=0,a3=0;
  for (int dd = tid; dd < Dq; dd += 64) {
    float xv = toF(x[off+dd]);
    a0 += xv*toF(wr[dd*Eq+0]);
    a1 += xv*toF(wr[dd*Eq+1]);
    a2 += xv*toF(wr[dd*Eq+2]);
    a3 += xv*toF(wr[dd*Eq+3]);
  }
#pragma unroll
  for (int o=32;o>=1;o>>=1) {
    a0 += __shfl_xor(a0,o); a1 += __shfl_xor(a1,o);
    a2 += __shfl_xor(a2,o); a3 += __shfl_xor(a3,o);
  }
  if (tid == 0) {
    a0 += toF(br[0]); a1 += toF(br[1]); a2 += toF(br[2]); a3 += toF(br[3]);
    float m = fmaxf(fmaxf(a0,a1),fmaxf(a2,a3));
    float e0=__expf(a0-m), e1=__expf(a1-m), e2=__expf(a2-m), e3=__expf(a3-m);
    float inv = 1.f/(e0+e1+e2+e3);
    float sc = cmb0[row >> 10];
    gates_t[0*BSq+row]=e0*inv*sc; gates_t[1*BSq+row]=e1*inv*sc;
    gates_t[2*BSq+row]=e2*inv*sc; gates_t[3*BSq+row]=e3*inv*sc;
  }
}

__global__ __launch_bounds__(64)
void router_kernel(const int* __restrict__ flag, const void* x, const void* wr,
                   const void* br, const float* cmb0, float* gates_t)
{
  if (*flag) router_body<bf16>((const bf16*)x, (const bf16*)wr, (const bf16*)br, cmb0, gates_t);
  else       router_body<float>((const float*)x, (const float*)wr, (const float*)br, cmb0, gates_t);
}

// ---------------- tiny gate networks ----------------
template<typename IT>
__device__ void gates_body(float* g1, float* lg, float* ffnw, float* stg0, float* stg1, float* sffn,
    const float* __restrict__ avg,
    const IT* __restrict__ arg_w1, const IT* __restrict__ arg_b1,
    const IT* __restrict__ arg_w2, const IT* __restrict__ arg_b2,
    const IT* __restrict__ taa_wg, const IT* __restrict__ taa_bg,
    const IT* __restrict__ ag_w, const IT* __restrict__ ag_b,
    float* __restrict__ cmb0, float* __restrict__ rs_tg0,
    float* __restrict__ rs_tg1, float* __restrict__ rs_ffn)
{
  int tid = threadIdx.x;
  {
    int b = tid >> 7, j = tid & 127;
    float a = toF(arg_b1[j]);
    for (int dd = 0; dd < Dq; dd++) a += avg[b*Dq+dd]*toF(arg_w1[dd*GATEq+j]);
    g1[b*GATEq+j] = gelu_f(a);
  }
  __syncthreads();
  if (tid < 2) {
    float a = toF(arg_b2[1]);
    for (int j = 0; j < GATEq; j++) a += g1[tid*GATEq+j]*toF(arg_w2[j*2+1]);
    ffnw[tid] = 1.f/(1.f+__expf(-a));
  } else if (tid < 6) {
    int b = (tid-2)>>1, c = (tid-2)&1;
    float a = toF(taa_bg[c]);
    for (int dd = 0; dd < Dq; dd++) a += avg[b*Dq+dd]*toF(taa_wg[dd*2+c]);
    lg[b*2+c] = a;
  } else if (tid < 10) {
    int b = (tid-6)>>1, c = (tid-6)&1;
    float a = toF(ag_b[c]);
    for (int dd = 0; dd < Dq; dd++) a += avg[b*Dq+dd]*toF(ag_w[dd*2+c]);
    lg[4 + b*2+c] = a;
  }
  __syncthreads();
  if (tid < Bq) {
    int b = tid;
    float t0 = lg[b*2], t1 = lg[b*2+1];
    float m = fmaxf(t0,t1);
    float e0=__expf(t0-m), e1=__expf(t1-m), inv=1.f/(e0+e1);
    float tg0 = e0*inv, tg1 = e1*inv;
    float a0 = lg[4+b*2], a1l = lg[4+b*2+1];
    m = fmaxf(a0,a1l);
    float f0=__expf(a0-m), f1=__expf(a1l-m); inv = 1.f/(f0+f1);
    float ag0 = f0*inv, ag1 = f1*inv;
    cmb0[b] = ag0*DEPTHF;
    stg0[b] = tg0*ag1*DEPTHF;
    stg1[b] = tg1*ag1*DEPTHF;
    sffn[b] = ffnw[b]*DEPTHF;
  }
  __syncthreads();
  for (int i = tid; i < BSq; i += 256) {
    int b = i >> 10;
    rs_tg0[i] = stg0[b]; rs_tg1[i] = stg1[b]; rs_ffn[i] = sffn[b];
  }
}

__global__ __launch_bounds__(256)
void gates_small_kernel(const int* __restrict__ flag, const float* avg,
    const void* arg_w1, const void* arg_b1, const void* arg_w2, const void* arg_b2,
    const void* taa_wg, const void* taa_bg, const void* ag_w, const void* ag_b,
    float* cmb0, float* rs_tg0, float* rs_tg1, float* rs_ffn)
{
  __shared__ float g1[Bq*GATEq];
  __shared__ float lg[8];
  __shared__ float ffnw[2], stg0[2], stg1[2], sffn[2];
  if (*flag) gates_body<bf16>(g1, lg, ffnw, stg0, stg1, sffn, avg,
      (const bf16*)arg_w1,(const bf16*)arg_b1,(const bf16*)arg_w2,(const bf16*)arg_b2,
      (const bf16*)taa_wg,(const bf16*)taa_bg,(const bf16*)ag_w,(const bf16*)ag_b,
      cmb0, rs_tg0, rs_tg1, rs_ffn);
  else gates_body<float>(g1, lg, ffnw, stg0, stg1, sffn, avg,
      (const float*)arg_w1,(const float*)arg_b1,(const float*)arg_w2,(const float*)arg_b2,
      (const float*)taa_wg,(const float*)taa_bg,(const float*)ag_w,(const float*)ag_b,
      cmb0, rs_tg0, rs_tg1, rs_ffn);
}

extern "C" void kernel_launch(void* const* d_in, const int* in_sizes, int n_in,
                              void* d_out, int out_size, void* d_ws, size_t ws_size,
                              hipStream_t stream) {
  const void* x      = d_in[0];
  const void* arg_w1 = d_in[1];  const void* arg_b1 = d_in[2];
  const void* arg_w2 = d_in[3];  const void* arg_b2 = d_in[4];
  const void* moe_wr = d_in[5];  const void* moe_br = d_in[6];
  const void* moe_wq = d_in[7];  const void* moe_bq = d_in[8];
  const void* moe_wk = d_in[9];  const void* moe_bk = d_in[10];
  const void* moe_wv = d_in[11]; const void* moe_bv = d_in[12];
  const void* moe_wo = d_in[13]; const void* moe_bo = d_in[14];
  const void* sp_wq  = d_in[15]; const void* sp_bq  = d_in[16];
  const void* sp_wk  = d_in[17]; const void* sp_bk  = d_in[18];
  const void* sp_wv  = d_in[19]; const void* sp_bv  = d_in[20];
  const void* sp_wo  = d_in[21]; const void* sp_bo  = d_in[22];
  const void* pf_wq  = d_in[23]; const void* pf_bq  = d_in[24];
  const void* pf_wk  = d_in[25]; const void* pf_bk  = d_in[26];
  const void* pf_wv  = d_in[27]; const void* pf_bv  = d_in[28];
  const void* pf_wo  = d_in[29]; const void* pf_bo  = d_in[30];
  const void* pf_wf  = d_in[31];
  const void* taa_wg = d_in[32]; const void* taa_bg = d_in[33];
  const void* ag_w   = d_in[34]; const void* ag_b   = d_in[35];
  const void* ffn_w1 = d_in[36]; const void* ffn_b1 = d_in[37];
  const void* ffn_w2 = d_in[38]; const void* ffn_b2 = d_in[39];
  const void* n1_g   = d_in[40]; const void* n1_b   = d_in[41];
  const void* n2_g   = d_in[42]; const void* n2_b   = d_in[43];
  const void* n3_g   = d_in[44]; const void* n3_b   = d_in[45];

  char* w = (char*)d_ws;
  const size_t MB = 1024*1024;
  float* acc   = (float*)(w);              // 8 MB fp32 combined attention accumulator
  bf16*  Qb    = (bf16*)(w + 8*MB);        // 4 MB
  bf16*  Kb    = (bf16*)(w + 12*MB);       // 4 MB
  bf16*  Vb    = (bf16*)(w + 16*MB);       // 4 MB
  bf16*  Hb    = (bf16*)(w + 20*MB);       // 4 MB
  float* kv    = (float*)(w + 24*MB);      // 2 MB
  float* zb    = kv + (size_t)Bq*Hq*Mq*DHq;
  float* avgp  = zb + Bq*Hq*Mq;
  float* gates_t = avgp + Bq*Dq;
  float* rs_tg0 = gates_t + (size_t)Eq*BSq;
  float* rs_tg1 = rs_tg0 + BSq;
  float* rs_ffn = rs_tg1 + BSq;
  float* cmb0  = rs_ffn + BSq;
  int*   dflag = (int*)(cmb0 + 2);
  // FFN-phase aliases (all dead by then)
  bf16* x1    = Hb;
  bf16* ffn_h = (bf16*)(w);                // 16 MB over acc+Qb+Kb
  bf16* tmpb  = Vb;
  bf16* x2    = Qb;

  detect_kernel<<<1, 256, 0, stream>>>((const unsigned*)x, dflag);
  hipMemsetAsync(kv, 0, (size_t)(Bq*Hq*Mq*DHq + Bq*Hq*Mq)*sizeof(float), stream);

  dim3 gG(BSq/64, Dq/64);
  dim3 gG1(BSq/64, FFq/64);
  int nAttnBlk = Bq*Hq*(Sq/8);

  avg_kernel<<<(Bq*Dq+255)/256, 256, 0, stream>>>(dflag, x, avgp);
  gates_small_kernel<<<1, 256, 0, stream>>>(dflag, avgp, arg_w1, arg_b1, arg_w2, arg_b2,
      taa_wg, taa_bg, ag_w, ag_b, cmb0, rs_tg0, rs_tg1, rs_ffn);
  router_kernel<<<BSq, 64, 0, stream>>>(dflag, x, moe_wr, moe_br, cmb0, gates_t);

  // ---- MoE expert attentions (rowscale = gate_e * ag0 * DEPTH, accumulated into acc) ----
  for (int e = 0; e < Eq; e++) {
    unsigned wOff = (unsigned)e*Dq*Dq, bOff = (unsigned)e*Dq;
    gemm_xw<<<gG, 256, 0, stream>>>(dflag, x, moe_wq, moe_bq, wOff, bOff, nullptr, Qb, BSq, Dq, Dq, 0, 0);
    gemm_xw<<<gG, 256, 0, stream>>>(dflag, x, moe_wk, moe_bk, wOff, bOff, nullptr, Kb, BSq, Dq, Dq, 0, 0);
    gemm_xw<<<gG, 256, 0, stream>>>(dflag, x, moe_wv, moe_bv, wOff, bOff, nullptr, Vb, BSq, Dq, Dq, 0, 0);
    attn_kernel<0><<<nAttnBlk, 256, 0, stream>>>(Qb, Kb, Vb, Hb);
    gemm_bwf<<<gG, 256, 0, stream>>>(dflag, Hb, moe_wo, moe_bo, wOff, bOff,
        gates_t + (size_t)e*BSq, acc, BSq, Dq, Dq, (e>0)?1:0, 0);
  }

  // ---- sparse attention (rowscale = tg0 * ag1 * DEPTH) ----
  gemm_xw<<<gG, 256, 0, stream>>>(dflag, x, sp_wq, sp_bq, 0, 0, nullptr, Qb, BSq, Dq, Dq, 0, 0);
  gemm_xw<<<gG, 256, 0, stream>>>(dflag, x, sp_wk, sp_bk, 0, 0, nullptr, Kb, BSq, Dq, Dq, 0, 0);
  gemm_xw<<<gG, 256, 0, stream>>>(dflag, x, sp_wv, sp_bv, 0, 0, nullptr, Vb, BSq, Dq, Dq, 0, 0);
  attn_kernel<1><<<nAttnBlk, 256, 0, stream>>>(Qb, Kb, Vb, Hb);
  gemm_bwf<<<gG, 256, 0, stream>>>(dflag, Hb, sp_wo, sp_bo, 0, 0, rs_tg0, acc, BSq, Dq, Dq, 1, 0);

  // ---- performer attention (rowscale = tg1 * ag1 * DEPTH) ----
  gemm_xw<<<gG, 256, 0, stream>>>(dflag, x, pf_wq, pf_bq, 0, 0, nullptr, Qb, BSq, Dq, Dq, 0, 0);
  gemm_xw<<<gG, 256, 0, stream>>>(dflag, x, pf_wk, pf_bk, 0, 0, nullptr, Kb, BSq, Dq, Dq, 0, 0);
  gemm_xw<<<gG, 256, 0, stream>>>(dflag, x, pf_wv, pf_bv, 0, 0, nullptr, Vb, BSq, Dq, Dq, 0, 0);
  {
    dim3 gKV(Bq*Hq, 8);
    perf_kv_kernel<<<gKV, 256, 0, stream>>>(dflag, Kb, Vb, pf_wf, kv, zb);
  }
  perf_out_kernel<<<Bq*Hq*(Sq/64), 256, 0, stream>>>(dflag, Qb, pf_wf, kv, zb, Hb);
  gemm_bwf<<<gG, 256, 0, stream>>>(dflag, Hb, pf_wo, pf_bo, 0, 0, rs_tg1, acc, BSq, Dq, Dq, 1, 0);

  // ---- LN1: x + acc -> x1 (bf16) ----
  ln_kernel<<<BSq, 256, 0, stream>>>(dflag, x, acc, nullptr, n1_g, n1_b, x1, 0);

  // ---- FFN ----
  gemm_bwb<<<gG1, 256, 0, stream>>>(dflag, x1, ffn_w1, ffn_b1, 0, 0, nullptr, ffn_h, BSq, FFq, Dq, 0, 1);
  gemm_bwb<<<gG, 256, 0, stream>>>(dflag, ffn_h, ffn_w2, ffn_b2, 0, 0, rs_ffn, tmpb, BSq, Dq, FFq, 0, 0);

  // ---- LN2: x1 + ffn_out -> x2 ; LN3: x2 -> d_out ----
  ln_kernel<<<BSq, 256, 0, stream>>>(dflag, nullptr, x1, tmpb, n2_g, n2_b, x2, 1);
  ln_kernel<<<BSq, 256, 0, stream>>>(dflag, nullptr, x2, nullptr, n3_g, n3_b, d_out, 2);
}

// Round 4
// 3131.713 us; speedup vs baseline: 1.8083x; 1.8083x over previous
//
#include <hip/hip_runtime.h>
#include <hip/hip_bf16.h>
#include <math.h>

#define Bq 2
#define Sq 1024
#define Dq 1024
#define Hq 16
#define DHq 64
#define FFq 4096
#define Eq 4
#define Kq 64
#define Mq 256
#define GATEq 128
#define BSq (Bq*Sq)
#define DEPTHF 1.25f
#define SCALEF 0.125f
#define DD (Dq*Dq)

typedef __hip_bfloat16 bf16;
typedef __attribute__((ext_vector_type(8))) __bf16 bf16x8;
typedef __attribute__((ext_vector_type(4))) float f32x4;

__device__ __forceinline__ float toF(float v){ return v; }
__device__ __forceinline__ float toF(bf16 v){ return __bfloat162float(v); }
__device__ __forceinline__ void stF(float* p, size_t i, float v){ p[i] = v; }
__device__ __forceinline__ void stF(bf16* p, size_t i, float v){ p[i] = __float2bfloat16(v); }
__device__ __forceinline__ float gelu_f(float x){
  const float c = 0.7978845608028654f;
  return 0.5f*x*(1.0f + tanhf(c*(x + 0.044715f*x*x*x)));
}
__device__ __forceinline__ unsigned short bfb(float f){
  bf16 h = __float2bfloat16(f);
  return *(unsigned short*)&h;
}
// async global->LDS, 16B per lane; lds pointer must be wave-uniform (chunk base)
__device__ __forceinline__ void async_lds16(const void* g, void* lds) {
  __builtin_amdgcn_global_load_lds(
      (const __attribute__((address_space(1))) void*)(unsigned long long)(uintptr_t)g,
      (__attribute__((address_space(3))) void*)(unsigned)(uintptr_t)lds, 16, 0, 0);
}

// ---------------- dtype detector ----------------
__global__ __launch_bounds__(256)
void detect_kernel(const unsigned* __restrict__ xw, int* __restrict__ flag)
{
  __shared__ int cnt;
  if (threadIdx.x == 0) cnt = 0;
  __syncthreads();
  int c = 0;
  for (int i = threadIdx.x; i < 4096; i += 256) {
    unsigned e = (xw[i] >> 7) & 0xFFu;
    c += (e >= 0x70u && e <= 0x8Fu) ? 1 : 0;
  }
#pragma unroll
  for (int o = 32; o >= 1; o >>= 1) c += __shfl_xor(c, o);
  if ((threadIdx.x & 63) == 0) atomicAdd(&cnt, c);
  __syncthreads();
  if (threadIdx.x == 0) *flag = (cnt > 2048) ? 1 : 0;
}

// ---------------- convert x -> bf16 ----------------
__global__ __launch_bounds__(256)
void conv_x_kernel(const int* __restrict__ flag, const void* __restrict__ x, bf16* __restrict__ xb)
{
  int f = *flag;
  int i0 = (blockIdx.x*256 + threadIdx.x)*4;
  if (i0 >= BSq*Dq) return;
  if (f) {
    const bf16* s = (const bf16*)x;
#pragma unroll
    for (int k=0;k<4;k++) xb[i0+k] = s[i0+k];
  } else {
    const float* s = (const float*)x;
#pragma unroll
    for (int k=0;k<4;k++) xb[i0+k] = __float2bfloat16(s[i0+k]);
  }
}

// ---------------- pack all biases into bf16 arena ----------------
template<typename IT>
__device__ void packseg(bf16* dst, const IT* src, int len)
{
  for (int i = threadIdx.x; i < len; i += 256) dst[i] = __float2bfloat16(toF(src[i]));
}
__global__ __launch_bounds__(256)
void pack_bias_kernel(const int* __restrict__ flag, bf16* arena,
    const void* bq, const void* bk, const void* bv, const void* bo,
    const void* sq, const void* sk, const void* sv, const void* so,
    const void* pq, const void* pk, const void* pv, const void* po,
    const void* f1, const void* f2)
{
  int f = *flag;
  if (f) {
    packseg(arena+0,     (const bf16*)bq, 4096); packseg(arena+4096,  (const bf16*)bk, 4096);
    packseg(arena+8192,  (const bf16*)bv, 4096); packseg(arena+12288, (const bf16*)bo, 4096);
    packseg(arena+16384, (const bf16*)sq, 1024); packseg(arena+17408, (const bf16*)sk, 1024);
    packseg(arena+18432, (const bf16*)sv, 1024); packseg(arena+19456, (const bf16*)so, 1024);
    packseg(arena+20480, (const bf16*)pq, 1024); packseg(arena+21504, (const bf16*)pk, 1024);
    packseg(arena+22528, (const bf16*)pv, 1024); packseg(arena+23552, (const bf16*)po, 1024);
    packseg(arena+24576, (const bf16*)f1, 4096); packseg(arena+28672, (const bf16*)f2, 1024);
  } else {
    packseg(arena+0,     (const float*)bq, 4096); packseg(arena+4096,  (const float*)bk, 4096);
    packseg(arena+8192,  (const float*)bv, 4096); packseg(arena+12288, (const float*)bo, 4096);
    packseg(arena+16384, (const float*)sq, 1024); packseg(arena+17408, (const float*)sk, 1024);
    packseg(arena+18432, (const float*)sv, 1024); packseg(arena+19456, (const float*)so, 1024);
    packseg(arena+20480, (const float*)pq, 1024); packseg(arena+21504, (const float*)pk, 1024);
    packseg(arena+22528, (const float*)pv, 1024); packseg(arena+23552, (const float*)po, 1024);
    packseg(arena+24576, (const float*)f1, 4096); packseg(arena+28672, (const float*)f2, 1024);
  }
}

// ---------------- MFMA GEMM: C(2048xN) = act(A(2048xK) @ W(KxN) + bias) * rowscale [+C] ----------------
template<typename WT>
__device__ void gemm_core(bf16* As, unsigned* Bs,
    const bf16* __restrict__ A, const WT* __restrict__ W,
    const bf16* __restrict__ barena, int biasOff,
    const float* __restrict__ rowscale, bf16* __restrict__ C,
    int N, int K, int accum, int act)
{
  int tid = threadIdx.x;
  int lane = tid & 63, wave = tid >> 6;
  int wr = wave >> 1, wc = wave & 1;
  int bm = blockIdx.x * 128, bn = blockIdx.y * 128;

  // A staging: 8 chunks of 16 rows; wave stages chunks {wave, wave+4}; lane->16B
  int arow1 = wave*16 + (lane>>2);
  int akey = (arow1 >> 1) & 3;
  int acol = ((lane & 3) ^ akey) * 8;
  const bf16* aP1 = A + (size_t)(bm + arow1)*K + acol;
  const bf16* aP2 = A + (size_t)(bm + arow1 + 64)*K + acol;   // key identical (row+64)
  bf16* ldsA1 = As + wave*512;
  bf16* ldsA2 = As + (wave+4)*512;

  // B staging: thread -> k-pair kp (0..15), 8 columns nb8
  int kp = tid >> 4, nb8 = (tid & 15)*8;
  const WT* wP = W + (size_t)(2*kp)*N + bn + nb8;
  unsigned* bDst = Bs + kp*132 + nb8;

  f32x4 acc[4][4];
#pragma unroll
  for (int i=0;i<4;i++)
#pragma unroll
    for (int j=0;j<4;j++) acc[i][j] = (f32x4){0.f,0.f,0.f,0.f};

  int m = lane & 15, q = lane >> 4;
  int akey2 = (m >> 1) & 3;
  int aq = (q ^ akey2) * 8;

  for (int k0 = 0; k0 < K; k0 += 32) {
    __syncthreads();
    async_lds16(aP1, ldsA1);
    async_lds16(aP2, ldsA2);
    aP1 += 32; aP2 += 32;
    unsigned p[8];
    if constexpr (sizeof(WT) == 2) {
      const unsigned* s0 = (const unsigned*)wP;
      const unsigned* s1 = (const unsigned*)(wP + N);
      uint4 r0 = *(const uint4*)s0;
      uint4 r1 = *(const uint4*)s1;
      p[0] = (r0.x & 0xFFFFu) | (r1.x << 16);  p[1] = (r0.x >> 16) | (r1.x & 0xFFFF0000u);
      p[2] = (r0.y & 0xFFFFu) | (r1.y << 16);  p[3] = (r0.y >> 16) | (r1.y & 0xFFFF0000u);
      p[4] = (r0.z & 0xFFFFu) | (r1.z << 16);  p[5] = (r0.z >> 16) | (r1.z & 0xFFFF0000u);
      p[6] = (r0.w & 0xFFFFu) | (r1.w << 16);  p[7] = (r0.w >> 16) | (r1.w & 0xFFFF0000u);
    } else {
      const float* s0 = (const float*)wP;
      const float* s1 = (const float*)(wP + N);
#pragma unroll
      for (int e=0;e<8;e++)
        p[e] = (unsigned)bfb(s0[e]) | ((unsigned)bfb(s1[e]) << 16);
    }
    wP += (size_t)32*N;
    *(uint4*)(bDst)     = make_uint4(p[0],p[1],p[2],p[3]);
    *(uint4*)(bDst + 4) = make_uint4(p[4],p[5],p[6],p[7]);
    asm volatile("s_waitcnt vmcnt(0)" ::: "memory");
    __syncthreads();

    bf16x8 av[4], bv[4];
#pragma unroll
    for (int i=0;i<4;i++)
      av[i] = *(const bf16x8*)&As[(wr*64 + i*16 + m)*32 + aq];
#pragma unroll
    for (int j=0;j<4;j++) {
      int n = wc*64 + j*16 + m;
      unsigned b0 = Bs[(q*4+0)*132 + n];
      unsigned b1 = Bs[(q*4+1)*132 + n];
      unsigned b2 = Bs[(q*4+2)*132 + n];
      unsigned b3 = Bs[(q*4+3)*132 + n];
      uint4 bb = make_uint4(b0,b1,b2,b3);
      bv[j] = *(const bf16x8*)&bb;
    }
#pragma unroll
    for (int i=0;i<4;i++)
#pragma unroll
      for (int j=0;j<4;j++)
        acc[i][j] = __builtin_amdgcn_mfma_f32_16x16x32_bf16(av[i], bv[j], acc[i][j], 0, 0, 0);
  }

  // epilogue: C/D layout col=lane&15, row=(lane>>4)*4+reg
#pragma unroll
  for (int i=0;i<4;i++) {
    int row0 = bm + wr*64 + i*16 + q*4;
#pragma unroll
    for (int j=0;j<4;j++) {
      int col = bn + wc*64 + j*16 + m;
      float bvv = barena ? toF(barena[biasOff + col]) : 0.f;
#pragma unroll
      for (int r=0;r<4;r++) {
        float v = acc[i][j][r] + bvv;
        if (act) v = gelu_f(v);
        if (rowscale) v *= rowscale[row0 + r];
        size_t idx = (size_t)(row0 + r)*N + col;
        if (accum) v += toF(C[idx]);
        C[idx] = __float2bfloat16(v);
      }
    }
  }
}

__global__ __launch_bounds__(256)
void gemm_k(const int* __restrict__ flag, const bf16* A,
            const void* W0, const void* W1, const void* W2, long eOff,
            const bf16* barena, int biasOff, int biasZStride,
            const float* rowscale, bf16* Cbase, long czStride,
            int N, int K, int accum, int act)
{
  __shared__ bf16 As[128*32];
  __shared__ unsigned Bs[16*132];
  int z = blockIdx.z;
  const void* Wp = (z==0) ? W0 : (z==1) ? W1 : W2;
  bf16* C = Cbase + (size_t)z * czStride;
  int bOff = biasOff + z*biasZStride;
  if (*flag) gemm_core<bf16>(As, Bs, A, (const bf16*)Wp + eOff, barena, bOff, rowscale, C, N, K, accum, act);
  else       gemm_core<float>(As, Bs, A, (const float*)Wp + eOff, barena, bOff, rowscale, C, N, K, accum, act);
}

// ---------------- fused attention (dense / top-K sparse), 8 query rows / block ----------------
// O may alias Q (rows read fully before written)
template<int SPARSE>
__global__ __launch_bounds__(256)
void attn_kernel(const bf16* __restrict__ Q, const bf16* __restrict__ K,
                 const bf16* __restrict__ V, bf16* __restrict__ O)
{
  const int ROWS = 8;
  __shared__ float sc[ROWS][Sq];      // 32 KB
  __shared__ float qsf[ROWS][DHq];    // 2 KB
  __shared__ float rowl[ROWS];
  __shared__ __attribute__((aligned(16))) char uraw[128*72*2];  // ks (18.4 KB), later pw (8 KB)
  bf16 (*ks)[72] = (bf16(*)[72])uraw;
  float (*pw)[ROWS][DHq] = (float(*)[ROWS][DHq])uraw;

  int blk = blockIdx.x;
  int rb = blk & (Sq/ROWS - 1);
  int h  = (blk / (Sq/ROWS)) & (Hq-1);
  int b  = blk / ((Sq/ROWS)*Hq);
  int tid = threadIdx.x;
  size_t base = ((size_t)b*Sq)*Dq + (size_t)h*DHq;
  int q0 = rb*ROWS;

  for (int i = tid; i < ROWS*DHq; i += 256)
    qsf[i>>6][i&63] = toF(Q[base + (size_t)(q0 + (i>>6))*Dq + (i&63)]);

  // ---- scores: K staged in LDS tiles of 128 rows (2 threads/row, 64B each) ----
  for (int jt = 0; jt < 8; jt++) {
    int j0 = jt*128;
    __syncthreads();
    {
      int j = tid >> 1, hh = tid & 1;
      const uint4* src = (const uint4*)(K + base + (size_t)(j0+j)*Dq + hh*32);
      uint4* dst = (uint4*)&ks[j][hh*32];
      dst[0] = src[0]; dst[1] = src[1]; dst[2] = src[2]; dst[3] = src[3];
    }
    __syncthreads();
    {
      int j = tid & 127, rh = (tid >> 7) * 4;
      float a0=0.f,a1=0.f,a2=0.f,a3=0.f;
#pragma unroll
      for (int d8 = 0; d8 < 8; d8++) {
        uint4 kk4 = *(const uint4*)&ks[j][d8*8];
        const bf16* kkp = (const bf16*)&kk4;
#pragma unroll
        for (int e=0;e<8;e++) {
          float kv = toF(kkp[e]);
          int d = d8*8+e;
          a0 += qsf[rh+0][d]*kv; a1 += qsf[rh+1][d]*kv;
          a2 += qsf[rh+2][d]*kv; a3 += qsf[rh+3][d]*kv;
        }
      }
      int jj = j0 + j;
      sc[rh+0][jj]=a0*SCALEF; sc[rh+1][jj]=a1*SCALEF;
      sc[rh+2][jj]=a2*SCALEF; sc[rh+3][jj]=a3*SCALEF;
    }
  }
  __syncthreads();

  // ---- softmax (+ exact top-K threshold for sparse), 32 threads/row ----
  {
    int r = tid >> 5, sub = tid & 31;
    float thrf = -1e30f;
    if (SPARSE) {
      unsigned uu[32];
#pragma unroll
      for (int i=0;i<32;i++) {
        unsigned ub = __float_as_uint(sc[r][sub + 32*i]);
        uu[i] = (ub & 0x80000000u) ? ~ub : (ub | 0x80000000u);
      }
      unsigned lo = 0u;
#pragma unroll
      for (int bit = 31; bit >= 0; bit--) {
        unsigned cand = lo | (1u << bit);
        int c = 0;
#pragma unroll
        for (int i=0;i<32;i++) c += (uu[i] >= cand) ? 1 : 0;
#pragma unroll
        for (int o=16;o>=1;o>>=1) c += __shfl_xor(c, o, 32);
        if (c >= Kq) lo = cand;
      }
      thrf = (lo & 0x80000000u) ? __uint_as_float(lo & 0x7FFFFFFFu)
                                : __uint_as_float(~lo);
    }
    float mx = -1e30f;
    for (int j = sub; j < Sq; j += 32) {
      float f = sc[r][j];
      if (!SPARSE || f >= thrf) mx = fmaxf(mx, f);
    }
#pragma unroll
    for (int o=16;o>=1;o>>=1) mx = fmaxf(mx, __shfl_xor(mx, o, 32));
    float lsum = 0.f;
    for (int j = sub; j < Sq; j += 32) {
      float f = sc[r][j];
      float p = (!SPARSE || f >= thrf) ? __expf(f - mx) : 0.f;
      sc[r][j] = p;
      lsum += p;
    }
#pragma unroll
    for (int o=16;o>=1;o>>=1) lsum += __shfl_xor(lsum, o, 32);
    if (sub == 0) rowl[r] = fmaxf(lsum, 1e-30f);
  }
  __syncthreads();

  // ---- PV: wave w handles j in [w*256, w*256+256), coalesced 16B V loads ----
  {
    int w = tid >> 6, l = tid & 63;
    int dj = l >> 3, d8 = (l & 7)*8;
    float acc[8][8];
#pragma unroll
    for (int r=0;r<8;r++)
#pragma unroll
      for (int e=0;e<8;e++) acc[r][e] = 0.f;
    for (int rnd = 0; rnd < 32; rnd++) {
      int jj = w*256 + rnd*8 + dj;
      uint4 vv4 = *(const uint4*)&V[base + (size_t)jj*Dq + d8];
      const bf16* vp = (const bf16*)&vv4;
      float vf[8];
#pragma unroll
      for (int e=0;e<8;e++) vf[e] = toF(vp[e]);
      float p[8];
#pragma unroll
      for (int r=0;r<8;r++) p[r] = sc[r][jj];
#pragma unroll
      for (int r=0;r<8;r++)
#pragma unroll
        for (int e=0;e<8;e++) acc[r][e] += p[r]*vf[e];
    }
#pragma unroll
    for (int mask=8; mask<=32; mask<<=1)
#pragma unroll
      for (int r=0;r<8;r++)
#pragma unroll
        for (int e=0;e<8;e++) acc[r][e] += __shfl_xor(acc[r][e], mask);
    if (dj == 0) {
#pragma unroll
      for (int r=0;r<8;r++)
#pragma unroll
        for (int e=0;e<8;e++) pw[w][r][d8+e] = acc[r][e];
    }
  }
  __syncthreads();
  for (int i = tid; i < ROWS*DHq; i += 256) {
    int r = i >> 6, d = i & 63;
    float s = pw[0][r][d]+pw[1][r][d]+pw[2][r][d]+pw[3][r][d];
    O[base + (size_t)(q0+r)*Dq + d] = __float2bfloat16(s / rowl[r]);
  }
}

// ---------------- performer pass 1: kv = pk^T v, z = sum pk ----------------
template<typename WT>
__device__ void perf_kv_body(bf16* wfs, float* krow, float* vrow, float* pkrow,
                             const bf16* __restrict__ Kb, const bf16* __restrict__ V,
                             const WT* __restrict__ wf, float* __restrict__ kv,
                             float* __restrict__ z)
{
  const int SLEN = Sq/8;
  int bh = blockIdx.x;
  int chunk = blockIdx.y;
  int h = bh & (Hq-1), b = bh >> 4;
  int tid = threadIdx.x;
  for (int l = tid; l < DHq*Mq; l += 256)
    wfs[l] = __float2bfloat16(toF(wf[l]));
  int d = tid & 63, g = tid >> 6;
  float kvacc[64];
#pragma unroll
  for (int i=0;i<64;i++) kvacc[i]=0.f;
  float zacc = 0.f;
  size_t base = ((size_t)b*Sq)*Dq + (size_t)h*DHq;
  for (int s = chunk*SLEN; s < (chunk+1)*SLEN; s++) {
    __syncthreads();
    if (tid < 64)       krow[tid]    = toF(Kb[base + (size_t)s*Dq + tid]);
    else if (tid < 128) vrow[tid-64] = toF(V [base + (size_t)s*Dq + (tid-64)]);
    __syncthreads();
    float a = 0.f;
#pragma unroll
    for (int dd = 0; dd < DHq; dd++) a += krow[dd]*toF(wfs[dd*Mq + tid]);
    float pk = fmaxf(a, 0.f);
    pkrow[tid] = pk;
    zacc += pk;
    __syncthreads();
    float vd = vrow[d];
#pragma unroll
    for (int i = 0; i < 64; i++) kvacc[i] += pkrow[g*64+i]*vd;
  }
  float* kvp = kv + (size_t)bh*Mq*DHq;
  for (int i = 0; i < 64; i++) atomicAdd(&kvp[(size_t)(g*64+i)*DHq + d], kvacc[i]);
  atomicAdd(&z[(size_t)bh*Mq + tid], zacc);
}

__global__ __launch_bounds__(256)
void perf_kv_kernel(const int* __restrict__ flag, const bf16* Kb, const bf16* V,
                    const void* wf, float* kv, float* z)
{
  __shared__ bf16 wfs[DHq*Mq];
  __shared__ float krow[DHq], vrow[DHq], pkrow[Mq];
  if (*flag) perf_kv_body<bf16>(wfs, krow, vrow, pkrow, Kb, V, (const bf16*)wf, kv, z);
  else       perf_kv_body<float>(wfs, krow, vrow, pkrow, Kb, V, (const float*)wf, kv, z);
}

// ---------------- performer pass 2 (O may alias Q; per-s read-then-write) ----------------
template<typename WT>
__device__ void perf_out_body(bf16* wfs, float* qrow, float* pqrow, float* redn, float* redd,
                              const bf16* __restrict__ Q, const WT* __restrict__ wf,
                              const float* __restrict__ kv, const float* __restrict__ z,
                              bf16* __restrict__ O)
{
  const int TC = 64;
  int blk = blockIdx.x;
  int tc = blk & (Sq/TC - 1);
  int h = (blk / (Sq/TC)) & (Hq-1);
  int b = blk / ((Sq/TC)*Hq);
  int bh = b*Hq + h;
  int tid = threadIdx.x;
  for (int l = tid; l < DHq*Mq; l += 256)
    wfs[l] = __float2bfloat16(toF(wf[l]));
  int d = tid & 63, g = tid >> 6;
  size_t base = ((size_t)b*Sq)*Dq + (size_t)h*DHq;
  const float* kvp = kv + (size_t)bh*Mq*DHq;
  const float* zp  = z  + (size_t)bh*Mq;
  for (int s = tc*TC; s < (tc+1)*TC; s++) {
    __syncthreads();
    if (tid < 64) qrow[tid] = toF(Q[base + (size_t)s*Dq + tid]);
    __syncthreads();
    float a = 0.f;
#pragma unroll
    for (int dd = 0; dd < DHq; dd++) a += qrow[dd]*toF(wfs[dd*Mq + tid]);
    float pq = fmaxf(a, 0.f);
    pqrow[tid] = pq;
    float pd = pq * zp[tid];
#pragma unroll
    for (int o=32;o>=1;o>>=1) pd += __shfl_xor(pd, o);
    if ((tid & 63) == 0) redd[g] = pd;
    __syncthreads();
    float den = redd[0]+redd[1]+redd[2]+redd[3] + 1e-6f;
    float np = 0.f;
#pragma unroll
    for (int i = 0; i < 64; i++) np += pqrow[g*64+i]*kvp[(size_t)(g*64+i)*DHq + d];
    redn[g*DHq + d] = np;
    __syncthreads();
    if (g == 0) {
      float num = redn[0*DHq+d]+redn[1*DHq+d]+redn[2*DHq+d]+redn[3*DHq+d];
      stF(O, base + (size_t)s*Dq + d, num / den);
    }
  }
}

__global__ __launch_bounds__(256)
void perf_out_kernel(const int* __restrict__ flag, const bf16* Q, const void* wf,
                     const float* kv, const float* z, bf16* O)
{
  __shared__ bf16 wfs[DHq*Mq];
  __shared__ float qrow[DHq], pqrow[Mq];
  __shared__ float redn[4*DHq];
  __shared__ float redd[4];
  if (*flag) perf_out_body<bf16>(wfs, qrow, pqrow, redn, redd, Q, (const bf16*)wf, kv, z, O);
  else       perf_out_body<float>(wfs, qrow, pqrow, redn, redd, Q, (const float*)wf, kv, z, O);
}

// ---------------- LayerNorm ----------------
// mode 0: v = x(IT) + A(bf16)   -> bf16 out
// mode 1: v = A(bf16) + B(bf16) -> bf16 out
// mode 2: v = A(bf16)           -> IT out (d_out)
template<typename IT>
__device__ void ln_body(float* buf, float* red, const IT* __restrict__ xb,
                        const void* Ap, const void* Bp,
                        const IT* __restrict__ g, const IT* __restrict__ be,
                        void* out, int mode)
{
  int row = blockIdx.x;
  int tid = threadIdx.x;
  size_t off = (size_t)row*Dq;
  for (int dd = tid; dd < Dq; dd += 256) {
    float v;
    if (mode == 0)      v = toF(xb[off+dd]) + toF(((const bf16*)Ap)[off+dd]);
    else if (mode == 1) v = toF(((const bf16*)Ap)[off+dd]) + toF(((const bf16*)Bp)[off+dd]);
    else                v = toF(((const bf16*)Ap)[off+dd]);
    buf[dd] = v;
  }
  __syncthreads();
  float s = 0.f, q = 0.f;
  for (int dd = tid; dd < Dq; dd += 256) { float v = buf[dd]; s += v; q += v*v; }
#pragma unroll
  for (int o=32;o>=1;o>>=1) { s += __shfl_xor(s,o); q += __shfl_xor(q,o); }
  int w = tid >> 6;
  if ((tid & 63) == 0) { red[w] = s; red[4+w] = q; }
  __syncthreads();
  if (tid == 0) {
    float S1 = red[0]+red[1]+red[2]+red[3];
    float Q1 = red[4]+red[5]+red[6]+red[7];
    float mu = S1 / (float)Dq;
    float var = Q1 / (float)Dq - mu*mu;
    red[8] = mu; red[9] = rsqrtf(fmaxf(var, 0.f) + 1e-5f);
  }
  __syncthreads();
  float mu = red[8], inv = red[9];
  for (int dd = tid; dd < Dq; dd += 256) {
    float v = (buf[dd]-mu)*inv*toF(g[dd]) + toF(be[dd]);
    if (mode == 2) stF((IT*)out, off+dd, v);
    else           stF((bf16*)out, off+dd, v);
  }
}

__global__ __launch_bounds__(256)
void ln_kernel(const int* __restrict__ flag, const void* xb, const void* A, const void* Bv,
               const void* g, const void* be, void* out, int mode)
{
  __shared__ float buf[Dq];
  __shared__ float red[10];
  if (*flag) ln_body<bf16>(buf, red, (const bf16*)xb, A, Bv, (const bf16*)g, (const bf16*)be, out, mode);
  else       ln_body<float>(buf, red, (const float*)xb, A, Bv, (const float*)g, (const float*)be, out, mode);
}

// ---------------- avg over S ----------------
template<typename IT>
__device__ void avg_body(const IT* __restrict__ x, float* __restrict__ avg)
{
  int i = blockIdx.x*256 + threadIdx.x;
  if (i >= Bq*Dq) return;
  int b = i >> 10, dd = i & 1023;
  float s = 0.f;
  for (int ss = 0; ss < Sq; ss++) s += toF(x[((size_t)b*Sq+ss)*Dq + dd]);
  avg[i] = s * (1.0f/(float)Sq);
}
__global__ __launch_bounds__(256)
void avg_kernel(const int* __restrict__ flag, const void* x, float* avg)
{
  if (*flag) avg_body<bf16>((const bf16*)x, avg);
  else       avg_body<float>((const float*)x, avg);
}

// ---------------- MoE router (softmax over E, pre-scaled by ag0*DEPTH) ----------------
template<typename IT>
__device__ void router_body(const IT* __restrict__ x, const IT* __restrict__ wr,
                            const IT* __restrict__ br, const float* __restrict__ cmb0,
                            float* __restrict__ gates_t)
{
  int row = blockIdx.x;
  int tid = threadIdx.x;
  size_t off = (size_t)row*Dq;
  float a0=0,a1=0,a2=0,a3=0;
  for (int dd = tid; dd < Dq; dd += 64) {
    float xv = toF(x[off+dd]);
    a0 += xv*toF(wr[dd*Eq+0]);
    a1 += xv*toF(wr[dd*Eq+1]);
    a2 += xv*toF(wr[dd*Eq+2]);
    a3 += xv*toF(wr[dd*Eq+3]);
  }
#pragma unroll
  for (int o=32;o>=1;o>>=1) {
    a0 += __shfl_xor(a0,o); a1 += __shfl_xor(a1,o);
    a2 += __shfl_xor(a2,o); a3 += __shfl_xor(a3,o);
  }
  if (tid == 0) {
    a0 += toF(br[0]); a1 += toF(br[1]); a2 += toF(br[2]); a3 += toF(br[3]);
    float m = fmaxf(fmaxf(a0,a1),fmaxf(a2,a3));
    float e0=__expf(a0-m), e1=__expf(a1-m), e2=__expf(a2-m), e3=__expf(a3-m);
    float inv = 1.f/(e0+e1+e2+e3);
    float sc = cmb0[row >> 10];
    gates_t[0*BSq+row]=e0*inv*sc; gates_t[1*BSq+row]=e1*inv*sc;
    gates_t[2*BSq+row]=e2*inv*sc; gates_t[3*BSq+row]=e3*inv*sc;
  }
}
__global__ __launch_bounds__(64)
void router_kernel(const int* __restrict__ flag, const void* x, const void* wr,
                   const void* br, const float* cmb0, float* gates_t)
{
  if (*flag) router_body<bf16>((const bf16*)x, (const bf16*)wr, (const bf16*)br, cmb0, gates_t);
  else       router_body<float>((const float*)x, (const float*)wr, (const float*)br, cmb0, gates_t);
}

// ---------------- tiny gate networks ----------------
template<typename IT>
__device__ void gates_body(float* g1, float* lg, float* ffnw, float* stg0, float* stg1, float* sffn,
    const float* __restrict__ avg,
    const IT* __restrict__ arg_w1, const IT* __restrict__ arg_b1,
    const IT* __restrict__ arg_w2, const IT* __restrict__ arg_b2,
    const IT* __restrict__ taa_wg, const IT* __restrict__ taa_bg,
    const IT* __restrict__ ag_w, const IT* __restrict__ ag_b,
    float* __restrict__ cmb0, float* __restrict__ rs_tg0,
    float* __restrict__ rs_tg1, float* __restrict__ rs_ffn)
{
  int tid = threadIdx.x;
  {
    int b = tid >> 7, j = tid & 127;
    float a = toF(arg_b1[j]);
    for (int dd = 0; dd < Dq; dd++) a += avg[b*Dq+dd]*toF(arg_w1[dd*GATEq+j]);
    g1[b*GATEq+j] = gelu_f(a);
  }
  __syncthreads();
  if (tid < 2) {
    float a = toF(arg_b2[1]);
    for (int j = 0; j < GATEq; j++) a += g1[tid*GATEq+j]*toF(arg_w2[j*2+1]);
    ffnw[tid] = 1.f/(1.f+__expf(-a));
  } else if (tid < 6) {
    int b = (tid-2)>>1, c = (tid-2)&1;
    float a = toF(taa_bg[c]);
    for (int dd = 0; dd < Dq; dd++) a += avg[b*Dq+dd]*toF(taa_wg[dd*2+c]);
    lg[b*2+c] = a;
  } else if (tid < 10) {
    int b = (tid-6)>>1, c = (tid-6)&1;
    float a = toF(ag_b[c]);
    for (int dd = 0; dd < Dq; dd++) a += avg[b*Dq+dd]*toF(ag_w[dd*2+c]);
    lg[4 + b*2+c] = a;
  }
  __syncthreads();
  if (tid < Bq) {
    int b = tid;
    float t0 = lg[b*2], t1 = lg[b*2+1];
    float m = fmaxf(t0,t1);
    float e0=__expf(t0-m), e1=__expf(t1-m), inv=1.f/(e0+e1);
    float tg0 = e0*inv, tg1 = e1*inv;
    float a0 = lg[4+b*2], a1l = lg[4+b*2+1];
    m = fmaxf(a0,a1l);
    float f0=__expf(a0-m), f1=__expf(a1l-m); inv = 1.f/(f0+f1);
    float ag0 = f0*inv, ag1 = f1*inv;
    cmb0[b] = ag0*DEPTHF;
    stg0[b] = tg0*ag1*DEPTHF;
    stg1[b] = tg1*ag1*DEPTHF;
    sffn[b] = ffnw[b]*DEPTHF;
  }
  __syncthreads();
  for (int i = tid; i < BSq; i += 256) {
    int b = i >> 10;
    rs_tg0[i] = stg0[b]; rs_tg1[i] = stg1[b]; rs_ffn[i] = sffn[b];
  }
}
__global__ __launch_bounds__(256)
void gates_small_kernel(const int* __restrict__ flag, const float* avg,
    const void* arg_w1, const void* arg_b1, const void* arg_w2, const void* arg_b2,
    const void* taa_wg, const void* taa_bg, const void* ag_w, const void* ag_b,
    float* cmb0, float* rs_tg0, float* rs_tg1, float* rs_ffn)
{
  __shared__ float g1[Bq*GATEq];
  __shared__ float lg[8];
  __shared__ float ffnw[2], stg0[2], stg1[2], sffn[2];
  if (*flag) gates_body<bf16>(g1, lg, ffnw, stg0, stg1, sffn, avg,
      (const bf16*)arg_w1,(const bf16*)arg_b1,(const bf16*)arg_w2,(const bf16*)arg_b2,
      (const bf16*)taa_wg,(const bf16*)taa_bg,(const bf16*)ag_w,(const bf16*)ag_b,
      cmb0, rs_tg0, rs_tg1, rs_ffn);
  else gates_body<float>(g1, lg, ffnw, stg0, stg1, sffn, avg,
      (const float*)arg_w1,(const float*)arg_b1,(const float*)arg_w2,(const float*)arg_b2,
      (const float*)taa_wg,(const float*)taa_bg,(const float*)ag_w,(const float*)ag_b,
      cmb0, rs_tg0, rs_tg1, rs_ffn);
}

extern "C" void kernel_launch(void* const* d_in, const int* in_sizes, int n_in,
                              void* d_out, int out_size, void* d_ws, size_t ws_size,
                              hipStream_t stream) {
  const void* x      = d_in[0];
  const void* arg_w1 = d_in[1];  const void* arg_b1 = d_in[2];
  const void* arg_w2 = d_in[3];  const void* arg_b2 = d_in[4];
  const void* moe_wr = d_in[5];  const void* moe_br = d_in[6];
  const void* moe_wq = d_in[7];  const void* moe_bq = d_in[8];
  const void* moe_wk = d_in[9];  const void* moe_bk = d_in[10];
  const void* moe_wv = d_in[11]; const void* moe_bv = d_in[12];
  const void* moe_wo = d_in[13]; const void* moe_bo = d_in[14];
  const void* sp_wq  = d_in[15]; const void* sp_bq  = d_in[16];
  const void* sp_wk  = d_in[17]; const void* sp_bk  = d_in[18];
  const void* sp_wv  = d_in[19]; const void* sp_bv  = d_in[20];
  const void* sp_wo  = d_in[21]; const void* sp_bo  = d_in[22];
  const void* pf_wq  = d_in[23]; const void* pf_bq  = d_in[24];
  const void* pf_wk  = d_in[25]; const void* pf_bk  = d_in[26];
  const void* pf_wv  = d_in[27]; const void* pf_bv  = d_in[28];
  const void* pf_wo  = d_in[29]; const void* pf_bo  = d_in[30];
  const void* pf_wf  = d_in[31];
  const void* taa_wg = d_in[32]; const void* taa_bg = d_in[33];
  const void* ag_w   = d_in[34]; const void* ag_b   = d_in[35];
  const void* ffn_w1 = d_in[36]; const void* ffn_b1 = d_in[37];
  const void* ffn_w2 = d_in[38]; const void* ffn_b2 = d_in[39];
  const void* n1_g   = d_in[40]; const void* n1_b   = d_in[41];
  const void* n2_g   = d_in[42]; const void* n2_b   = d_in[43];
  const void* n3_g   = d_in[44]; const void* n3_b   = d_in[45];

  char* w = (char*)d_ws;
  const size_t MB = 1024*1024;
  bf16* xb   = (bf16*)(w);            // [0,4)
  bf16* accb = (bf16*)(w + 4*MB);     // [4,8)
  bf16* Qb   = (bf16*)(w + 8*MB);     // [8,12)  (also attention O, in place)
  bf16* Kb   = (bf16*)(w + 12*MB);    // [12,16)
  bf16* Vb   = (bf16*)(w + 16*MB);    // [16,20)
  char* book = w + 20*MB;
  float* rs_tg0 = (float*)book;
  float* rs_tg1 = rs_tg0 + BSq;
  float* rs_ffn = rs_tg1 + BSq;
  float* cmb0   = rs_ffn + BSq;
  float* avgp   = cmb0 + 16;
  float* gates_t= avgp + Bq*Dq;
  float* zb     = gates_t + Eq*BSq;
  int*   dflag  = (int*)(zb + Bq*Hq*Mq);
  bf16*  barena = (bf16*)(dflag + 16);
  float* kv     = (float*)(w + 21*MB); // [21,23)
  // FFN-phase aliases
  bf16* x1    = Vb;                    // [16,20)
  bf16* ffn_h = (bf16*)w;              // [0,16)
  bf16* tmpb  = (bf16*)(w + 21*MB);    // [21,25) over kv (dead)
  bf16* x2    = (bf16*)w;              // [0,4)

  detect_kernel<<<1, 256, 0, stream>>>((const unsigned*)x, dflag);
  hipMemsetAsync(kv, 0, (size_t)(Bq*Hq*Mq*DHq)*sizeof(float), stream);
  hipMemsetAsync(zb, 0, (size_t)(Bq*Hq*Mq)*sizeof(float), stream);

  conv_x_kernel<<<BSq*Dq/1024, 256, 0, stream>>>(dflag, x, xb);
  pack_bias_kernel<<<1, 256, 0, stream>>>(dflag, barena,
      moe_bq, moe_bk, moe_bv, moe_bo, sp_bq, sp_bk, sp_bv, sp_bo,
      pf_bq, pf_bk, pf_bv, pf_bo, ffn_b1, ffn_b2);
  avg_kernel<<<(Bq*Dq+255)/256, 256, 0, stream>>>(dflag, x, avgp);
  gates_small_kernel<<<1, 256, 0, stream>>>(dflag, avgp, arg_w1, arg_b1, arg_w2, arg_b2,
      taa_wg, taa_bg, ag_w, ag_b, cmb0, rs_tg0, rs_tg1, rs_ffn);
  router_kernel<<<BSq, 64, 0, stream>>>(dflag, x, moe_wr, moe_br, cmb0, gates_t);

  dim3 gQKV(16, 8, 3);
  dim3 gOP(16, 8, 1);
  dim3 gF1(16, 32, 1);
  int nAttnBlk = Bq*Hq*(Sq/8);
  long czQKV = (long)BSq*Dq;

  // ---- MoE expert attentions ----
  for (int e = 0; e < Eq; e++) {
    long eOff = (long)e*DD;
    gemm_k<<<gQKV, 256, 0, stream>>>(dflag, xb, moe_wq, moe_wk, moe_wv, eOff,
        barena, e*1024, 4096, nullptr, Qb, czQKV, Dq, Dq, 0, 0);
    attn_kernel<0><<<nAttnBlk, 256, 0, stream>>>(Qb, Kb, Vb, Qb);
    gemm_k<<<gOP, 256, 0, stream>>>(dflag, Qb, moe_wo, moe_wo, moe_wo, eOff,
        barena, 12288 + e*1024, 0, gates_t + (size_t)e*BSq, accb, 0, Dq, Dq, (e>0)?1:0, 0);
  }

  // ---- sparse attention ----
  gemm_k<<<gQKV, 256, 0, stream>>>(dflag, xb, sp_wq, sp_wk, sp_wv, 0,
      barena, 16384, 1024, nullptr, Qb, czQKV, Dq, Dq, 0, 0);
  attn_kernel<1><<<nAttnBlk, 256, 0, stream>>>(Qb, Kb, Vb, Qb);
  gemm_k<<<gOP, 256, 0, stream>>>(dflag, Qb, sp_wo, sp_wo, sp_wo, 0,
      barena, 19456, 0, rs_tg0, accb, 0, Dq, Dq, 1, 0);

  // ---- performer attention ----
  gemm_k<<<gQKV, 256, 0, stream>>>(dflag, xb, pf_wq, pf_wk, pf_wv, 0,
      barena, 20480, 1024, nullptr, Qb, czQKV, Dq, Dq, 0, 0);
  {
    dim3 gKV(Bq*Hq, 8);
    perf_kv_kernel<<<gKV, 256, 0, stream>>>(dflag, Kb, Vb, pf_wf, kv, zb);
  }
  perf_out_kernel<<<Bq*Hq*(Sq/64), 256, 0, stream>>>(dflag, Qb, pf_wf, kv, zb, Qb);
  gemm_k<<<gOP, 256, 0, stream>>>(dflag, Qb, pf_wo, pf_wo, pf_wo, 0,
      barena, 23552, 0, rs_tg1, accb, 0, Dq, Dq, 1, 0);

  // ---- LN1: x + accb -> x1 ----
  ln_kernel<<<BSq, 256, 0, stream>>>(dflag, x, accb, nullptr, n1_g, n1_b, x1, 0);

  // ---- FFN ----
  gemm_k<<<gF1, 256, 0, stream>>>(dflag, x1, ffn_w1, ffn_w1, ffn_w1, 0,
      barena, 24576, 0, nullptr, ffn_h, 0, FFq, Dq, 0, 1);
  gemm_k<<<gOP, 256, 0, stream>>>(dflag, ffn_h, ffn_w2, ffn_w2, ffn_w2, 0,
      barena, 28672, 0, rs_ffn, tmpb, 0, Dq, FFq, 0, 0);

  // ---- LN2, LN3 ----
  ln_kernel<<<BSq, 256, 0, stream>>>(dflag, nullptr, x1, tmpb, n2_g, n2_b, x2, 1);
  ln_kernel<<<BSq, 256, 0, stream>>>(dflag, nullptr, x2, nullptr, n3_g, n3_b, d_out, 2);
}

// Round 5
// 2351.974 us; speedup vs baseline: 2.4078x; 1.3315x over previous
//
#include <hip/hip_runtime.h>
#include <hip/hip_bf16.h>
#include <math.h>

#define Bq 2
#define Sq 1024
#define Dq 1024
#define Hq 16
#define DHq 64
#define FFq 4096
#define Eq 4
#define Kq 64
#define Mq 256
#define GATEq 128
#define BSq (Bq*Sq)
#define DEPTHF 1.25f
#define SCALEF 0.125f
#define DD (Dq*Dq)

typedef __hip_bfloat16 bf16;
typedef __attribute__((ext_vector_type(8))) __bf16 bf16x8;
typedef __attribute__((ext_vector_type(4))) float f32x4;

__device__ __forceinline__ float toF(float v){ return v; }
__device__ __forceinline__ float toF(bf16 v){ return __bfloat162float(v); }
__device__ __forceinline__ void stF(float* p, size_t i, float v){ p[i] = v; }
__device__ __forceinline__ void stF(bf16* p, size_t i, float v){ p[i] = __float2bfloat16(v); }
__device__ __forceinline__ float gelu_f(float x){
  const float c = 0.7978845608028654f;
  return 0.5f*x*(1.0f + tanhf(c*(x + 0.044715f*x*x*x)));
}
__device__ __forceinline__ unsigned short bfb(float f){
  bf16 h = __float2bfloat16(f);
  return *(unsigned short*)&h;
}
// async global->LDS, 16B per lane; lds pointer must be wave-uniform (chunk base)
__device__ __forceinline__ void async_lds16(const void* g, void* lds) {
  __builtin_amdgcn_global_load_lds(
      (const __attribute__((address_space(1))) void*)(unsigned long long)(uintptr_t)g,
      (__attribute__((address_space(3))) void*)(unsigned)(uintptr_t)lds, 16, 0, 0);
}

// ---------------- dtype detector ----------------
__global__ __launch_bounds__(256)
void detect_kernel(const unsigned* __restrict__ xw, int* __restrict__ flag)
{
  __shared__ int cnt;
  if (threadIdx.x == 0) cnt = 0;
  __syncthreads();
  int c = 0;
  for (int i = threadIdx.x; i < 4096; i += 256) {
    unsigned e = (xw[i] >> 7) & 0xFFu;
    c += (e >= 0x70u && e <= 0x8Fu) ? 1 : 0;
  }
#pragma unroll
  for (int o = 32; o >= 1; o >>= 1) c += __shfl_xor(c, o);
  if ((threadIdx.x & 63) == 0) atomicAdd(&cnt, c);
  __syncthreads();
  if (threadIdx.x == 0) *flag = (cnt > 2048) ? 1 : 0;
}

// ---------------- convert x -> bf16 ----------------
__global__ __launch_bounds__(256)
void conv_x_kernel(const int* __restrict__ flag, const void* __restrict__ x, bf16* __restrict__ xb)
{
  int f = *flag;
  int i0 = (blockIdx.x*256 + threadIdx.x)*4;
  if (i0 >= BSq*Dq) return;
  if (f) {
    const bf16* s = (const bf16*)x;
#pragma unroll
    for (int k=0;k<4;k++) xb[i0+k] = s[i0+k];
  } else {
    const float* s = (const float*)x;
#pragma unroll
    for (int k=0;k<4;k++) xb[i0+k] = __float2bfloat16(s[i0+k]);
  }
}

// ---------------- pack all biases into bf16 arena ----------------
template<typename IT>
__device__ void packseg(bf16* dst, const IT* src, int len)
{
  for (int i = threadIdx.x; i < len; i += 256) dst[i] = __float2bfloat16(toF(src[i]));
}
__global__ __launch_bounds__(256)
void pack_bias_kernel(const int* __restrict__ flag, bf16* arena,
    const void* bq, const void* bk, const void* bv, const void* bo,
    const void* sq, const void* sk, const void* sv, const void* so,
    const void* pq, const void* pk, const void* pv, const void* po,
    const void* f1, const void* f2)
{
  int f = *flag;
  if (f) {
    packseg(arena+0,     (const bf16*)bq, 4096); packseg(arena+4096,  (const bf16*)bk, 4096);
    packseg(arena+8192,  (const bf16*)bv, 4096); packseg(arena+12288, (const bf16*)bo, 4096);
    packseg(arena+16384, (const bf16*)sq, 1024); packseg(arena+17408, (const bf16*)sk, 1024);
    packseg(arena+18432, (const bf16*)sv, 1024); packseg(arena+19456, (const bf16*)so, 1024);
    packseg(arena+20480, (const bf16*)pq, 1024); packseg(arena+21504, (const bf16*)pk, 1024);
    packseg(arena+22528, (const bf16*)pv, 1024); packseg(arena+23552, (const bf16*)po, 1024);
    packseg(arena+24576, (const bf16*)f1, 4096); packseg(arena+28672, (const bf16*)f2, 1024);
  } else {
    packseg(arena+0,     (const float*)bq, 4096); packseg(arena+4096,  (const float*)bk, 4096);
    packseg(arena+8192,  (const float*)bv, 4096); packseg(arena+12288, (const float*)bo, 4096);
    packseg(arena+16384, (const float*)sq, 1024); packseg(arena+17408, (const float*)sk, 1024);
    packseg(arena+18432, (const float*)sv, 1024); packseg(arena+19456, (const float*)so, 1024);
    packseg(arena+20480, (const float*)pq, 1024); packseg(arena+21504, (const float*)pk, 1024);
    packseg(arena+22528, (const float*)pv, 1024); packseg(arena+23552, (const float*)po, 1024);
    packseg(arena+24576, (const float*)f1, 4096); packseg(arena+28672, (const float*)f2, 1024);
  }
}

// ---------------- MFMA GEMM: C(2048xN) = act(A(2048xK) @ W(KxN) + bias) * rowscale [+C] ----------------
template<typename WT>
__device__ void gemm_core(bf16* As, unsigned* Bs,
    const bf16* __restrict__ A, const WT* __restrict__ W,
    const bf16* __restrict__ barena, int biasOff,
    const float* __restrict__ rowscale, bf16* __restrict__ C,
    int N, int K, int accum, int act)
{
  int tid = threadIdx.x;
  int lane = tid & 63, wave = tid >> 6;
  int wr = wave >> 1, wc = wave & 1;
  int bm = blockIdx.x * 128, bn = blockIdx.y * 128;

  int arow1 = wave*16 + (lane>>2);
  int akey = (arow1 >> 1) & 3;
  int acol = ((lane & 3) ^ akey) * 8;
  const bf16* aP1 = A + (size_t)(bm + arow1)*K + acol;
  const bf16* aP2 = A + (size_t)(bm + arow1 + 64)*K + acol;
  bf16* ldsA1 = As + wave*512;
  bf16* ldsA2 = As + (wave+4)*512;

  int kp = tid >> 4, nb8 = (tid & 15)*8;
  const WT* wP = W + (size_t)(2*kp)*N + bn + nb8;
  unsigned* bDst = Bs + kp*132 + nb8;

  f32x4 acc[4][4];
#pragma unroll
  for (int i=0;i<4;i++)
#pragma unroll
    for (int j=0;j<4;j++) acc[i][j] = (f32x4){0.f,0.f,0.f,0.f};

  int m = lane & 15, q = lane >> 4;
  int akey2 = (m >> 1) & 3;
  int aq = (q ^ akey2) * 8;

  for (int k0 = 0; k0 < K; k0 += 32) {
    __syncthreads();
    async_lds16(aP1, ldsA1);
    async_lds16(aP2, ldsA2);
    aP1 += 32; aP2 += 32;
    unsigned p[8];
    if constexpr (sizeof(WT) == 2) {
      const unsigned* s0 = (const unsigned*)wP;
      const unsigned* s1 = (const unsigned*)(wP + N);
      uint4 r0 = *(const uint4*)s0;
      uint4 r1 = *(const uint4*)s1;
      p[0] = (r0.x & 0xFFFFu) | (r1.x << 16);  p[1] = (r0.x >> 16) | (r1.x & 0xFFFF0000u);
      p[2] = (r0.y & 0xFFFFu) | (r1.y << 16);  p[3] = (r0.y >> 16) | (r1.y & 0xFFFF0000u);
      p[4] = (r0.z & 0xFFFFu) | (r1.z << 16);  p[5] = (r0.z >> 16) | (r1.z & 0xFFFF0000u);
      p[6] = (r0.w & 0xFFFFu) | (r1.w << 16);  p[7] = (r0.w >> 16) | (r1.w & 0xFFFF0000u);
    } else {
      const float* s0 = (const float*)wP;
      const float* s1 = (const float*)(wP + N);
#pragma unroll
      for (int e=0;e<8;e++)
        p[e] = (unsigned)bfb(s0[e]) | ((unsigned)bfb(s1[e]) << 16);
    }
    wP += (size_t)32*N;
    *(uint4*)(bDst)     = make_uint4(p[0],p[1],p[2],p[3]);
    *(uint4*)(bDst + 4) = make_uint4(p[4],p[5],p[6],p[7]);
    asm volatile("s_waitcnt vmcnt(0)" ::: "memory");
    __syncthreads();

    bf16x8 av[4], bv[4];
#pragma unroll
    for (int i=0;i<4;i++)
      av[i] = *(const bf16x8*)&As[(wr*64 + i*16 + m)*32 + aq];
#pragma unroll
    for (int j=0;j<4;j++) {
      int n = wc*64 + j*16 + m;
      unsigned b0 = Bs[(q*4+0)*132 + n];
      unsigned b1 = Bs[(q*4+1)*132 + n];
      unsigned b2 = Bs[(q*4+2)*132 + n];
      unsigned b3 = Bs[(q*4+3)*132 + n];
      uint4 bb = make_uint4(b0,b1,b2,b3);
      bv[j] = *(const bf16x8*)&bb;
    }
#pragma unroll
    for (int i=0;i<4;i++)
#pragma unroll
      for (int j=0;j<4;j++)
        acc[i][j] = __builtin_amdgcn_mfma_f32_16x16x32_bf16(av[i], bv[j], acc[i][j], 0, 0, 0);
  }

#pragma unroll
  for (int i=0;i<4;i++) {
    int row0 = bm + wr*64 + i*16 + q*4;
#pragma unroll
    for (int j=0;j<4;j++) {
      int col = bn + wc*64 + j*16 + m;
      float bvv = barena ? toF(barena[biasOff + col]) : 0.f;
#pragma unroll
      for (int r=0;r<4;r++) {
        float v = acc[i][j][r] + bvv;
        if (act) v = gelu_f(v);
        if (rowscale) v *= rowscale[row0 + r];
        size_t idx = (size_t)(row0 + r)*N + col;
        if (accum) v += toF(C[idx]);
        C[idx] = __float2bfloat16(v);
      }
    }
  }
}

__global__ __launch_bounds__(256)
void gemm_k(const int* __restrict__ flag, const bf16* A,
            const void* W0, const void* W1, const void* W2, long eOff,
            const bf16* barena, int biasOff, int biasZStride,
            const float* rowscale, bf16* Cbase, long czStride,
            int N, int K, int accum, int act)
{
  __shared__ bf16 As[128*32];
  __shared__ unsigned Bs[16*132];
  int z = blockIdx.z;
  const void* Wp = (z==0) ? W0 : (z==1) ? W1 : W2;
  bf16* C = Cbase + (size_t)z * czStride;
  int bOff = biasOff + z*biasZStride;
  if (*flag) gemm_core<bf16>(As, Bs, A, (const bf16*)Wp + eOff, barena, bOff, rowscale, C, N, K, accum, act);
  else       gemm_core<float>(As, Bs, A, (const float*)Wp + eOff, barena, bOff, rowscale, C, N, K, accum, act);
}

// ---------------- V transpose: V(b,s,h,d) -> Vt(b,h,d,s) ----------------
__global__ __launch_bounds__(256)
void vtrans_kernel(const bf16* __restrict__ V, bf16* __restrict__ Vt)
{
  __shared__ bf16 t[64][72];     // 72 = 64 + 8 pad; rows 144 B (16B aligned)
  int bh = blockIdx.x;           // b*16 + h
  int sc_ = blockIdx.y;          // S/64 chunks
  int b = bh >> 4, h = bh & 15;
  int tid = threadIdx.x;
  {
    int s = tid >> 2, dd = (tid & 3) * 16;
    const bf16* src = &V[((size_t)b*Sq + sc_*64 + s)*Dq + h*64 + dd];
    uint4 a0 = *(const uint4*)src;
    uint4 a1 = *(const uint4*)(src + 8);
    *(uint4*)&t[s][dd]     = a0;
    *(uint4*)&t[s][dd + 8] = a1;
  }
  __syncthreads();
  {
    int d = tid >> 2, sp = (tid & 3) * 16;
    unsigned short buf[16];
#pragma unroll
    for (int e = 0; e < 16; e++) {
      bf16 v = t[sp + e][d];
      buf[e] = *(unsigned short*)&v;
    }
    bf16* dst = &Vt[((size_t)bh*DHq + d)*Sq + sc_*64 + sp];
    *(uint4*)dst       = *(uint4*)&buf[0];
    *(uint4*)(dst + 8) = *(uint4*)&buf[8];
  }
}

// ---------------- MFMA fused attention (dense / exact top-K sparse) ----------------
// One block = 16 query rows of one (b,h). O may alias Q.
template<int SPARSE>
__global__ __launch_bounds__(256)
void attn_kernel(const bf16* __restrict__ Q, const bf16* __restrict__ K,
                 const bf16* __restrict__ Vt, bf16* __restrict__ O)
{
  const int PAST = 1032;                    // pa stride (bf16), row = 2064 B (16B-aligned)
  __shared__ bf16 pa[16*PAST];              // 33 KB: p in A-operand layout
  __shared__ float partA[64], partB[64];
  __shared__ int cntb[2][64];

  int blk = blockIdx.x;
  int rb = blk & 63;
  int h  = (blk >> 6) & 15;
  int b  = blk >> 10;
  int tid = threadIdx.x, lane = tid & 63, wave = tid >> 6;
  int m = lane & 15, q = lane >> 4;
  size_t base = ((size_t)b*Sq)*Dq + (size_t)h*DHq;
  int q0 = rb*16;

  // Q A-frags (k=0..31, 32..63)
  const bf16* qrow = &Q[base + (size_t)(q0+m)*Dq + q*8];
  bf16x8 aq0 = *(const bf16x8*)qrow;
  bf16x8 aq1 = *(const bf16x8*)(qrow + 32);

  // ---- QK^T: wave covers score cols [wave*256, wave*256+256), scores in regs ----
  f32x4 cc[16];
#pragma unroll
  for (int t = 0; t < 16; t++) {
    int j0 = wave*256 + t*16;
    const bf16* kp = &K[base + (size_t)(j0+m)*Dq + q*8];
    bf16x8 b0 = *(const bf16x8*)kp;
    bf16x8 b1 = *(const bf16x8*)(kp + 32);
    f32x4 c = {0.f,0.f,0.f,0.f};
    c = __builtin_amdgcn_mfma_f32_16x16x32_bf16(aq0, b0, c, 0, 0, 0);
    c = __builtin_amdgcn_mfma_f32_16x16x32_bf16(aq1, b1, c, 0, 0, 0);
#pragma unroll
    for (int r=0;r<4;r++) c[r] *= SCALEF;
    cc[t] = c;
  }

  // ---- sparse: exact kth-largest per row via bit-descend on monotone uint map ----
  unsigned lo[4] = {0u,0u,0u,0u};
  unsigned uu[SPARSE ? 64 : 4];
  if (SPARSE) {
#pragma unroll
    for (int t=0;t<16;t++)
#pragma unroll
      for (int r=0;r<4;r++) {
        unsigned ub = __float_as_uint(cc[t][r]);
        uu[t*4+r] = (ub & 0x80000000u) ? ~ub : (ub | 0x80000000u);
      }
    for (int bit = 31; bit >= 0; bit--) {
      int par = bit & 1;
      unsigned cand[4];
      int c4[4] = {0,0,0,0};
#pragma unroll
      for (int r=0;r<4;r++) cand[r] = lo[r] | (1u << bit);
#pragma unroll
      for (int t=0;t<16;t++)
#pragma unroll
        for (int r=0;r<4;r++) c4[r] += (uu[t*4+r] >= cand[r]) ? 1 : 0;
#pragma unroll
      for (int o=1;o<16;o<<=1)
#pragma unroll
        for (int r=0;r<4;r++) c4[r] += __shfl_xor(c4[r], o);
      if (m == 0) {
#pragma unroll
        for (int r=0;r<4;r++) cntb[par][wave*16 + q*4 + r] = c4[r];
      }
      __syncthreads();
#pragma unroll
      for (int r=0;r<4;r++) {
        int row = q*4 + r;
        int tot = cntb[par][row] + cntb[par][16+row] + cntb[par][32+row] + cntb[par][48+row];
        if (tot >= Kq) lo[r] = cand[r];
      }
    }
  }

  // ---- row max (global max is always in top-K, so no mask needed) ----
  float mrow[4];
#pragma unroll
  for (int r=0;r<4;r++) {
    float v = -1e30f;
#pragma unroll
    for (int t=0;t<16;t++) v = fmaxf(v, cc[t][r]);
#pragma unroll
    for (int o=1;o<16;o<<=1) v = fmaxf(v, __shfl_xor(v, o));
    mrow[r] = v;
  }
  if (m == 0) {
#pragma unroll
    for (int r=0;r<4;r++) partA[wave*16 + q*4 + r] = mrow[r];
  }
  __syncthreads();
#pragma unroll
  for (int r=0;r<4;r++) {
    int row = q*4 + r;
    mrow[r] = fmaxf(fmaxf(partA[row], partA[16+row]), fmaxf(partA[32+row], partA[48+row]));
  }

  // ---- p = exp(s - m) (masked for sparse), write bf16 to pa, accumulate row sums ----
  float rsum[4] = {0.f,0.f,0.f,0.f};
#pragma unroll
  for (int t=0;t<16;t++) {
    int col = wave*256 + t*16 + m;
#pragma unroll
    for (int r=0;r<4;r++) {
      float p;
      if (SPARSE) p = (uu[t*4+r] >= lo[r]) ? __expf(cc[t][r] - mrow[r]) : 0.f;
      else        p = __expf(cc[t][r] - mrow[r]);
      rsum[r] += p;
      pa[(q*4+r)*PAST + col] = __float2bfloat16(p);
    }
  }
#pragma unroll
  for (int r=0;r<4;r++)
#pragma unroll
    for (int o=1;o<16;o<<=1) rsum[r] += __shfl_xor(rsum[r], o);
  if (m == 0) {
#pragma unroll
    for (int r=0;r<4;r++) partB[wave*16 + q*4 + r] = rsum[r];
  }
  __syncthreads();   // also makes pa visible for PV
#pragma unroll
  for (int r=0;r<4;r++) {
    int row = q*4 + r;
    rsum[r] = partB[row] + partB[16+row] + partB[32+row] + partB[48+row];
    rsum[r] = fmaxf(rsum[r], 1e-30f);
  }

  // ---- PV: wave covers dh cols [wave*16, wave*16+16); B-frags from transposed V ----
  const bf16* vtp = &Vt[((size_t)(b*Hq + h)*DHq + wave*16 + m)*Sq];
  f32x4 oc = {0.f,0.f,0.f,0.f};
#pragma unroll 8
  for (int ks = 0; ks < 32; ks++) {
    bf16x8 af = *(const bf16x8*)&pa[m*PAST + ks*32 + q*8];
    bf16x8 bv = *(const bf16x8*)&vtp[ks*32 + q*8];
    oc = __builtin_amdgcn_mfma_f32_16x16x32_bf16(af, bv, oc, 0, 0, 0);
  }
#pragma unroll
  for (int r=0;r<4;r++) {
    O[base + (size_t)(q0 + q*4 + r)*Dq + wave*16 + m] = __float2bfloat16(oc[r] / rsum[r]);
  }
}

// ---------------- performer pass 1: kv = pk^T v, z = sum pk ----------------
template<typename WT>
__device__ void perf_kv_body(bf16* wfs, float* krow, float* vrow, float* pkrow,
                             const bf16* __restrict__ Kb, const bf16* __restrict__ V,
                             const WT* __restrict__ wf, float* __restrict__ kv,
                             float* __restrict__ z)
{
  const int SLEN = Sq/8;
  int bh = blockIdx.x;
  int chunk = blockIdx.y;
  int h = bh & (Hq-1), b = bh >> 4;
  int tid = threadIdx.x;
  for (int l = tid; l < DHq*Mq; l += 256)
    wfs[l] = __float2bfloat16(toF(wf[l]));
  int d = tid & 63, g = tid >> 6;
  float kvacc[64];
#pragma unroll
  for (int i=0;i<64;i++) kvacc[i]=0.f;
  float zacc = 0.f;
  size_t base = ((size_t)b*Sq)*Dq + (size_t)h*DHq;
  for (int s = chunk*SLEN; s < (chunk+1)*SLEN; s++) {
    __syncthreads();
    if (tid < 64)       krow[tid]    = toF(Kb[base + (size_t)s*Dq + tid]);
    else if (tid < 128) vrow[tid-64] = toF(V [base + (size_t)s*Dq + (tid-64)]);
    __syncthreads();
    float a = 0.f;
#pragma unroll
    for (int dd = 0; dd < DHq; dd++) a += krow[dd]*toF(wfs[dd*Mq + tid]);
    float pk = fmaxf(a, 0.f);
    pkrow[tid] = pk;
    zacc += pk;
    __syncthreads();
    float vd = vrow[d];
#pragma unroll
    for (int i = 0; i < 64; i++) kvacc[i] += pkrow[g*64+i]*vd;
  }
  float* kvp = kv + (size_t)bh*Mq*DHq;
  for (int i = 0; i < 64; i++) atomicAdd(&kvp[(size_t)(g*64+i)*DHq + d], kvacc[i]);
  atomicAdd(&z[(size_t)bh*Mq + tid], zacc);
}

__global__ __launch_bounds__(256)
void perf_kv_kernel(const int* __restrict__ flag, const bf16* Kb, const bf16* V,
                    const void* wf, float* kv, float* z)
{
  __shared__ bf16 wfs[DHq*Mq];
  __shared__ float krow[DHq], vrow[DHq], pkrow[Mq];
  if (*flag) perf_kv_body<bf16>(wfs, krow, vrow, pkrow, Kb, V, (const bf16*)wf, kv, z);
  else       perf_kv_body<float>(wfs, krow, vrow, pkrow, Kb, V, (const float*)wf, kv, z);
}

// ---------------- performer pass 2 (O may alias Q) ----------------
template<typename WT>
__device__ void perf_out_body(bf16* wfs, float* qrow, float* pqrow, float* redn, float* redd,
                              const bf16* __restrict__ Q, const WT* __restrict__ wf,
                              const float* __restrict__ kv, const float* __restrict__ z,
                              bf16* __restrict__ O)
{
  const int TC = 64;
  int blk = blockIdx.x;
  int tc = blk & (Sq/TC - 1);
  int h = (blk / (Sq/TC)) & (Hq-1);
  int b = blk / ((Sq/TC)*Hq);
  int bh = b*Hq + h;
  int tid = threadIdx.x;
  for (int l = tid; l < DHq*Mq; l += 256)
    wfs[l] = __float2bfloat16(toF(wf[l]));
  int d = tid & 63, g = tid >> 6;
  size_t base = ((size_t)b*Sq)*Dq + (size_t)h*DHq;
  const float* kvp = kv + (size_t)bh*Mq*DHq;
  const float* zp  = z  + (size_t)bh*Mq;
  for (int s = tc*TC; s < (tc+1)*TC; s++) {
    __syncthreads();
    if (tid < 64) qrow[tid] = toF(Q[base + (size_t)s*Dq + tid]);
    __syncthreads();
    float a = 0.f;
#pragma unroll
    for (int dd = 0; dd < DHq; dd++) a += qrow[dd]*toF(wfs[dd*Mq + tid]);
    float pq = fmaxf(a, 0.f);
    pqrow[tid] = pq;
    float pd = pq * zp[tid];
#pragma unroll
    for (int o=32;o>=1;o>>=1) pd += __shfl_xor(pd, o);
    if ((tid & 63) == 0) redd[g] = pd;
    __syncthreads();
    float den = redd[0]+redd[1]+redd[2]+redd[3] + 1e-6f;
    float np = 0.f;
#pragma unroll
    for (int i = 0; i < 64; i++) np += pqrow[g*64+i]*kvp[(size_t)(g*64+i)*DHq + d];
    redn[g*DHq + d] = np;
    __syncthreads();
    if (g == 0) {
      float num = redn[0*DHq+d]+redn[1*DHq+d]+redn[2*DHq+d]+redn[3*DHq+d];
      stF(O, base + (size_t)s*Dq + d, num / den);
    }
  }
}

__global__ __launch_bounds__(256)
void perf_out_kernel(const int* __restrict__ flag, const bf16* Q, const void* wf,
                     const float* kv, const float* z, bf16* O)
{
  __shared__ bf16 wfs[DHq*Mq];
  __shared__ float qrow[DHq], pqrow[Mq];
  __shared__ float redn[4*DHq];
  __shared__ float redd[4];
  if (*flag) perf_out_body<bf16>(wfs, qrow, pqrow, redn, redd, Q, (const bf16*)wf, kv, z, O);
  else       perf_out_body<float>(wfs, qrow, pqrow, redn, redd, Q, (const float*)wf, kv, z, O);
}

// ---------------- LayerNorm ----------------
template<typename IT>
__device__ void ln_body(float* buf, float* red, const IT* __restrict__ xb,
                        const void* Ap, const void* Bp,
                        const IT* __restrict__ g, const IT* __restrict__ be,
                        void* out, int mode)
{
  int row = blockIdx.x;
  int tid = threadIdx.x;
  size_t off = (size_t)row*Dq;
  for (int dd = tid; dd < Dq; dd += 256) {
    float v;
    if (mode == 0)      v = toF(xb[off+dd]) + toF(((const bf16*)Ap)[off+dd]);
    else if (mode == 1) v = toF(((const bf16*)Ap)[off+dd]) + toF(((const bf16*)Bp)[off+dd]);
    else                v = toF(((const bf16*)Ap)[off+dd]);
    buf[dd] = v;
  }
  __syncthreads();
  float s = 0.f, q = 0.f;
  for (int dd = tid; dd < Dq; dd += 256) { float v = buf[dd]; s += v; q += v*v; }
#pragma unroll
  for (int o=32;o>=1;o>>=1) { s += __shfl_xor(s,o); q += __shfl_xor(q,o); }
  int w = tid >> 6;
  if ((tid & 63) == 0) { red[w] = s; red[4+w] = q; }
  __syncthreads();
  if (tid == 0) {
    float S1 = red[0]+red[1]+red[2]+red[3];
    float Q1 = red[4]+red[5]+red[6]+red[7];
    float mu = S1 / (float)Dq;
    float var = Q1 / (float)Dq - mu*mu;
    red[8] = mu; red[9] = rsqrtf(fmaxf(var, 0.f) + 1e-5f);
  }
  __syncthreads();
  float mu = red[8], inv = red[9];
  for (int dd = tid; dd < Dq; dd += 256) {
    float v = (buf[dd]-mu)*inv*toF(g[dd]) + toF(be[dd]);
    if (mode == 2) stF((IT*)out, off+dd, v);
    else           stF((bf16*)out, off+dd, v);
  }
}

__global__ __launch_bounds__(256)
void ln_kernel(const int* __restrict__ flag, const void* xb, const void* A, const void* Bv,
               const void* g, const void* be, void* out, int mode)
{
  __shared__ float buf[Dq];
  __shared__ float red[10];
  if (*flag) ln_body<bf16>(buf, red, (const bf16*)xb, A, Bv, (const bf16*)g, (const bf16*)be, out, mode);
  else       ln_body<float>(buf, red, (const float*)xb, A, Bv, (const float*)g, (const float*)be, out, mode);
}

// ---------------- avg over S ----------------
template<typename IT>
__device__ void avg_body(const IT* __restrict__ x, float* __restrict__ avg)
{
  int i = blockIdx.x*256 + threadIdx.x;
  if (i >= Bq*Dq) return;
  int b = i >> 10, dd = i & 1023;
  float s = 0.f;
  for (int ss = 0; ss < Sq; ss++) s += toF(x[((size_t)b*Sq+ss)*Dq + dd]);
  avg[i] = s * (1.0f/(float)Sq);
}
__global__ __launch_bounds__(256)
void avg_kernel(const int* __restrict__ flag, const void* x, float* avg)
{
  if (*flag) avg_body<bf16>((const bf16*)x, avg);
  else       avg_body<float>((const float*)x, avg);
}

// ---------------- MoE router ----------------
template<typename IT>
__device__ void router_body(const IT* __restrict__ x, const IT* __restrict__ wr,
                            const IT* __restrict__ br, const float* __restrict__ cmb0,
                            float* __restrict__ gates_t)
{
  int row = blockIdx.x;
  int tid = threadIdx.x;
  size_t off = (size_t)row*Dq;
  float a0=0,a1=0,a2=0,a3=0;
  for (int dd = tid; dd < Dq; dd += 64) {
    float xv = toF(x[off+dd]);
    a0 += xv*toF(wr[dd*Eq+0]);
    a1 += xv*toF(wr[dd*Eq+1]);
    a2 += xv*toF(wr[dd*Eq+2]);
    a3 += xv*toF(wr[dd*Eq+3]);
  }
#pragma unroll
  for (int o=32;o>=1;o>>=1) {
    a0 += __shfl_xor(a0,o); a1 += __shfl_xor(a1,o);
    a2 += __shfl_xor(a2,o); a3 += __shfl_xor(a3,o);
  }
  if (tid == 0) {
    a0 += toF(br[0]); a1 += toF(br[1]); a2 += toF(br[2]); a3 += toF(br[3]);
    float m = fmaxf(fmaxf(a0,a1),fmaxf(a2,a3));
    float e0=__expf(a0-m), e1=__expf(a1-m), e2=__expf(a2-m), e3=__expf(a3-m);
    float inv = 1.f/(e0+e1+e2+e3);
    float sc = cmb0[row >> 10];
    gates_t[0*BSq+row]=e0*inv*sc; gates_t[1*BSq+row]=e1*inv*sc;
    gates_t[2*BSq+row]=e2*inv*sc; gates_t[3*BSq+row]=e3*inv*sc;
  }
}
__global__ __launch_bounds__(64)
void router_kernel(const int* __restrict__ flag, const void* x, const void* wr,
                   const void* br, const float* cmb0, float* gates_t)
{
  if (*flag) router_body<bf16>((const bf16*)x, (const bf16*)wr, (const bf16*)br, cmb0, gates_t);
  else       router_body<float>((const float*)x, (const float*)wr, (const float*)br, cmb0, gates_t);
}

// ---------------- tiny gate networks ----------------
template<typename IT>
__device__ void gates_body(float* g1, float* lg, float* ffnw, float* stg0, float* stg1, float* sffn,
    const float* __restrict__ avg,
    const IT* __restrict__ arg_w1, const IT* __restrict__ arg_b1,
    const IT* __restrict__ arg_w2, const IT* __restrict__ arg_b2,
    const IT* __restrict__ taa_wg, const IT* __restrict__ taa_bg,
    const IT* __restrict__ ag_w, const IT* __restrict__ ag_b,
    float* __restrict__ cmb0, float* __restrict__ rs_tg0,
    float* __restrict__ rs_tg1, float* __restrict__ rs_ffn)
{
  int tid = threadIdx.x;
  {
    int b = tid >> 7, j = tid & 127;
    float a = toF(arg_b1[j]);
    for (int dd = 0; dd < Dq; dd++) a += avg[b*Dq+dd]*toF(arg_w1[dd*GATEq+j]);
    g1[b*GATEq+j] = gelu_f(a);
  }
  __syncthreads();
  if (tid < 2) {
    float a = toF(arg_b2[1]);
    for (int j = 0; j < GATEq; j++) a += g1[tid*GATEq+j]*toF(arg_w2[j*2+1]);
    ffnw[tid] = 1.f/(1.f+__expf(-a));
  } else if (tid < 6) {
    int b = (tid-2)>>1, c = (tid-2)&1;
    float a = toF(taa_bg[c]);
    for (int dd = 0; dd < Dq; dd++) a += avg[b*Dq+dd]*toF(taa_wg[dd*2+c]);
    lg[b*2+c] = a;
  } else if (tid < 10) {
    int b = (tid-6)>>1, c = (tid-6)&1;
    float a = toF(ag_b[c]);
    for (int dd = 0; dd < Dq; dd++) a += avg[b*Dq+dd]*toF(ag_w[dd*2+c]);
    lg[4 + b*2+c] = a;
  }
  __syncthreads();
  if (tid < Bq) {
    int b = tid;
    float t0 = lg[b*2], t1 = lg[b*2+1];
    float m = fmaxf(t0,t1);
    float e0=__expf(t0-m), e1=__expf(t1-m), inv=1.f/(e0+e1);
    float tg0 = e0*inv, tg1 = e1*inv;
    float a0 = lg[4+b*2], a1l = lg[4+b*2+1];
    m = fmaxf(a0,a1l);
    float f0=__expf(a0-m), f1=__expf(a1l-m); inv = 1.f/(f0+f1);
    float ag0 = f0*inv, ag1 = f1*inv;
    cmb0[b] = ag0*DEPTHF;
    stg0[b] = tg0*ag1*DEPTHF;
    stg1[b] = tg1*ag1*DEPTHF;
    sffn[b] = ffnw[b]*DEPTHF;
  }
  __syncthreads();
  for (int i = tid; i < BSq; i += 256) {
    int b = i >> 10;
    rs_tg0[i] = stg0[b]; rs_tg1[i] = stg1[b]; rs_ffn[i] = sffn[b];
  }
}
__global__ __launch_bounds__(256)
void gates_small_kernel(const int* __restrict__ flag, const float* avg,
    const void* arg_w1, const void* arg_b1, const void* arg_w2, const void* arg_b2,
    const void* taa_wg, const void* taa_bg, const void* ag_w, const void* ag_b,
    float* cmb0, float* rs_tg0, float* rs_tg1, float* rs_ffn)
{
  __shared__ float g1[Bq*GATEq];
  __shared__ float lg[8];
  __shared__ float ffnw[2], stg0[2], stg1[2], sffn[2];
  if (*flag) gates_body<bf16>(g1, lg, ffnw, stg0, stg1, sffn, avg,
      (const bf16*)arg_w1,(const bf16*)arg_b1,(const bf16*)arg_w2,(const bf16*)arg_b2,
      (const bf16*)taa_wg,(const bf16*)taa_bg,(const bf16*)ag_w,(const bf16*)ag_b,
      cmb0, rs_tg0, rs_tg1, rs_ffn);
  else gates_body<float>(g1, lg, ffnw, stg0, stg1, sffn, avg,
      (const float*)arg_w1,(const float*)arg_b1,(const float*)arg_w2,(const float*)arg_b2,
      (const float*)taa_wg,(const float*)taa_bg,(const float*)ag_w,(const float*)ag_b,
      cmb0, rs_tg0, rs_tg1, rs_ffn);
}

extern "C" void kernel_launch(void* const* d_in, const int* in_sizes, int n_in,
                              void* d_out, int out_size, void* d_ws, size_t ws_size,
                              hipStream_t stream) {
  const void* x      = d_in[0];
  const void* arg_w1 = d_in[1];  const void* arg_b1 = d_in[2];
  const void* arg_w2 = d_in[3];  const void* arg_b2 = d_in[4];
  const void* moe_wr = d_in[5];  const void* moe_br = d_in[6];
  const void* moe_wq = d_in[7];  const void* moe_bq = d_in[8];
  const void* moe_wk = d_in[9];  const void* moe_bk = d_in[10];
  const void* moe_wv = d_in[11]; const void* moe_bv = d_in[12];
  const void* moe_wo = d_in[13]; const void* moe_bo = d_in[14];
  const void* sp_wq  = d_in[15]; const void* sp_bq  = d_in[16];
  const void* sp_wk  = d_in[17]; const void* sp_bk  = d_in[18];
  const void* sp_wv  = d_in[19]; const void* sp_bv  = d_in[20];
  const void* sp_wo  = d_in[21]; const void* sp_bo  = d_in[22];
  const void* pf_wq  = d_in[23]; const void* pf_bq  = d_in[24];
  const void* pf_wk  = d_in[25]; const void* pf_bk  = d_in[26];
  const void* pf_wv  = d_in[27]; const void* pf_bv  = d_in[28];
  const void* pf_wo  = d_in[29]; const void* pf_bo  = d_in[30];
  const void* pf_wf  = d_in[31];
  const void* taa_wg = d_in[32]; const void* taa_bg = d_in[33];
  const void* ag_w   = d_in[34]; const void* ag_b   = d_in[35];
  const void* ffn_w1 = d_in[36]; const void* ffn_b1 = d_in[37];
  const void* ffn_w2 = d_in[38]; const void* ffn_b2 = d_in[39];
  const void* n1_g   = d_in[40]; const void* n1_b   = d_in[41];
  const void* n2_g   = d_in[42]; const void* n2_b   = d_in[43];
  const void* n3_g   = d_in[44]; const void* n3_b   = d_in[45];

  char* w = (char*)d_ws;
  const size_t MB = 1024*1024;
  bf16* xb   = (bf16*)(w);            // [0,4)
  bf16* accb = (bf16*)(w + 4*MB);     // [4,8)
  bf16* Qb   = (bf16*)(w + 8*MB);     // [8,12)  (also attention O, in place)
  bf16* Kb   = (bf16*)(w + 12*MB);    // [12,16)
  bf16* Vb   = (bf16*)(w + 16*MB);    // [16,20)
  char* book = w + 20*MB;
  float* rs_tg0 = (float*)book;
  float* rs_tg1 = rs_tg0 + BSq;
  float* rs_ffn = rs_tg1 + BSq;
  float* cmb0   = rs_ffn + BSq;
  float* avgp   = cmb0 + 16;
  float* gates_t= avgp + Bq*Dq;
  float* zb     = gates_t + Eq*BSq;
  int*   dflag  = (int*)(zb + Bq*Hq*Mq);
  bf16*  barena = (bf16*)(dflag + 16);
  bf16*  Vt     = (bf16*)(w + 21*MB);  // [21,25) transposed V (b,h,d,s)
  float* kv     = (float*)(w + 21*MB); // [21,23) performer phase only (after attn)
  // FFN-phase aliases
  bf16* x1    = Vb;                    // [16,20)
  bf16* ffn_h = (bf16*)w;              // [0,16)
  bf16* tmpb  = (bf16*)(w + 21*MB);    // [21,25) over kv/Vt (dead)
  bf16* x2    = (bf16*)w;              // [0,4)

  detect_kernel<<<1, 256, 0, stream>>>((const unsigned*)x, dflag);
  hipMemsetAsync(zb, 0, (size_t)(Bq*Hq*Mq)*sizeof(float), stream);

  conv_x_kernel<<<BSq*Dq/1024, 256, 0, stream>>>(dflag, x, xb);
  pack_bias_kernel<<<1, 256, 0, stream>>>(dflag, barena,
      moe_bq, moe_bk, moe_bv, moe_bo, sp_bq, sp_bk, sp_bv, sp_bo,
      pf_bq, pf_bk, pf_bv, pf_bo, ffn_b1, ffn_b2);
  avg_kernel<<<(Bq*Dq+255)/256, 256, 0, stream>>>(dflag, x, avgp);
  gates_small_kernel<<<1, 256, 0, stream>>>(dflag, avgp, arg_w1, arg_b1, arg_w2, arg_b2,
      taa_wg, taa_bg, ag_w, ag_b, cmb0, rs_tg0, rs_tg1, rs_ffn);
  router_kernel<<<BSq, 64, 0, stream>>>(dflag, x, moe_wr, moe_br, cmb0, gates_t);

  dim3 gQKV(16, 8, 3);
  dim3 gOP(16, 8, 1);
  dim3 gF1(16, 32, 1);
  dim3 gVT(Bq*Hq, Sq/64);
  int nAttnBlk = Bq*Hq*(Sq/16);
  long czQKV = (long)BSq*Dq;

  // ---- MoE expert attentions ----
  for (int e = 0; e < Eq; e++) {
    long eOff = (long)e*DD;
    gemm_k<<<gQKV, 256, 0, stream>>>(dflag, xb, moe_wq, moe_wk, moe_wv, eOff,
        barena, e*1024, 4096, nullptr, Qb, czQKV, Dq, Dq, 0, 0);
    vtrans_kernel<<<gVT, 256, 0, stream>>>(Vb, Vt);
    attn_kernel<0><<<nAttnBlk, 256, 0, stream>>>(Qb, Kb, Vt, Qb);
    gemm_k<<<gOP, 256, 0, stream>>>(dflag, Qb, moe_wo, moe_wo, moe_wo, eOff,
        barena, 12288 + e*1024, 0, gates_t + (size_t)e*BSq, accb, 0, Dq, Dq, (e>0)?1:0, 0);
  }

  // ---- sparse attention ----
  gemm_k<<<gQKV, 256, 0, stream>>>(dflag, xb, sp_wq, sp_wk, sp_wv, 0,
      barena, 16384, 1024, nullptr, Qb, czQKV, Dq, Dq, 0, 0);
  vtrans_kernel<<<gVT, 256, 0, stream>>>(Vb, Vt);
  attn_kernel<1><<<nAttnBlk, 256, 0, stream>>>(Qb, Kb, Vt, Qb);
  gemm_k<<<gOP, 256, 0, stream>>>(dflag, Qb, sp_wo, sp_wo, sp_wo, 0,
      barena, 19456, 0, rs_tg0, accb, 0, Dq, Dq, 1, 0);

  // ---- performer attention (kv memset here: Vt region is dead now) ----
  gemm_k<<<gQKV, 256, 0, stream>>>(dflag, xb, pf_wq, pf_wk, pf_wv, 0,
      barena, 20480, 1024, nullptr, Qb, czQKV, Dq, Dq, 0, 0);
  hipMemsetAsync(kv, 0, (size_t)(Bq*Hq*Mq*DHq)*sizeof(float), stream);
  {
    dim3 gKV(Bq*Hq, 8);
    perf_kv_kernel<<<gKV, 256, 0, stream>>>(dflag, Kb, Vb, pf_wf, kv, zb);
  }
  perf_out_kernel<<<Bq*Hq*(Sq/64), 256, 0, stream>>>(dflag, Qb, pf_wf, kv, zb, Qb);
  gemm_k<<<gOP, 256, 0, stream>>>(dflag, Qb, pf_wo, pf_wo, pf_wo, 0,
      barena, 23552, 0, rs_tg1, accb, 0, Dq, Dq, 1, 0);

  // ---- LN1: x + accb -> x1 ----
  ln_kernel<<<BSq, 256, 0, stream>>>(dflag, x, accb, nullptr, n1_g, n1_b, x1, 0);

  // ---- FFN ----
  gemm_k<<<gF1, 256, 0, stream>>>(dflag, x1, ffn_w1, ffn_w1, ffn_w1, 0,
      barena, 24576, 0, nullptr, ffn_h, 0, FFq, Dq, 0, 1);
  gemm_k<<<gOP, 256, 0, stream>>>(dflag, ffn_h, ffn_w2, ffn_w2, ffn_w2, 0,
      barena, 28672, 0, rs_ffn, tmpb, 0, Dq, FFq, 0, 0);

  // ---- LN2, LN3 ----
  ln_kernel<<<BSq, 256, 0, stream>>>(dflag, nullptr, x1, tmpb, n2_g, n2_b, x2, 1);
  ln_kernel<<<BSq, 256, 0, stream>>>(dflag, nullptr, x2, nullptr, n3_g, n3_b, d_out, 2);
}